// Round 5
// baseline (1934.911 us; speedup 1.0000x reference)
//
#include <hip/hip_runtime.h>
#include <math.h>

#define BB 8
#define HH 384
#define WW 384
#define NPAR 6
#define DEL 10
#define MAXIT 12
#define NACC 24
#define HWPIX (HH*WW)
#define NRT 122                 // row tiles (3 rows each) covering rows 10..373
#define GRID_ITER (NRT*3*BB)    // 2928 blocks in k_iter
#define PITCH2 144              // LDS pitch (float4) for I2 stage (cols <= 140)
#define PITCH1 136              // LDS pitch (float4) for I1 stage (cols <= 130)

typedef float vf4 __attribute__((ext_vector_type(4)));
typedef vf4 uvf4 __attribute__((aligned(4)));      // 4B-aligned global dwordx4
typedef float f2v __attribute__((ext_vector_type(2), aligned(4)));
typedef float lf4 __attribute__((ext_vector_type(4)));  // 16B-aligned (LDS)

__device__ __forceinline__ vf4 ldv4(const float* p) { return *(const uvf4*)p; }

__device__ __forceinline__ float cubicw(float s) {
    s = fabsf(s);
    float s2 = s * s, s3 = s2 * s;
    float w1 = 1.5f * s3 - 2.5f * s2 + 1.0f;
    float w2 = -0.5f * s3 + 2.5f * s2 - 4.0f * s + 2.0f;
    return (s <= 1.0f) ? w1 : ((s < 2.0f) ? w2 : 0.0f);
}

// global fast-path bicubic (taps guaranteed in-bounds; used as fallback)
__device__ __forceinline__ void bicubic3_fast(const float* __restrict__ Ib, double xg, double yg, float Iw[3]) {
    double fx = floor(xg), fy = floor(yg);
    float tx = (float)(xg - fx), ty = (float)(yg - fy);
    int xi = (int)fx, yi = (int)fy;
    float wx[4], wyv[4];
#pragma unroll
    for (int k = 0; k < 4; k++) { wx[k] = cubicw(tx - (float)(k - 1)); wyv[k] = cubicw(ty - (float)(k - 1)); }
    Iw[0] = 0.f; Iw[1] = 0.f; Iw[2] = 0.f;
    const float* base = Ib + (yi - 1) * (WW * 3) + (xi - 1) * 3;
#pragma unroll
    for (int j = 0; j < 4; j++) {
        const float* r = base + j * (WW * 3);
        vf4 v0 = ldv4(r), v1 = ldv4(r + 4), v2 = ldv4(r + 8);
        float r0 = fmaf(wx[0], v0.x, 0.f); r0 = fmaf(wx[1], v0.w, r0); r0 = fmaf(wx[2], v1.z, r0); r0 = fmaf(wx[3], v2.y, r0);
        float r1 = fmaf(wx[0], v0.y, 0.f); r1 = fmaf(wx[1], v1.x, r1); r1 = fmaf(wx[2], v1.w, r1); r1 = fmaf(wx[3], v2.z, r1);
        float r2 = fmaf(wx[0], v0.z, 0.f); r2 = fmaf(wx[1], v1.y, r2); r2 = fmaf(wx[2], v2.x, r2); r2 = fmaf(wx[3], v2.w, r2);
        Iw[0] = fmaf(wyv[j], r0, Iw[0]);
        Iw[1] = fmaf(wyv[j], r1, Iw[1]);
        Iw[2] = fmaf(wyv[j], r2, Iw[2]);
    }
}

// general bicubic with clip-to-edge (k_final_map fallback)
__device__ __forceinline__ void bicubic3_gen(const float* __restrict__ Ib, double xg, double yg, float Iw[3]) {
    double fx = floor(xg), fy = floor(yg);
    int xi = (int)fx, yi = (int)fy;
    float tx = (float)(xg - fx), ty = (float)(yg - fy);
    float wx[4], wyv[4];
    int xx[4], yy[4];
#pragma unroll
    for (int k = 0; k < 4; k++) {
        wx[k] = cubicw(tx - (float)(k - 1)); wyv[k] = cubicw(ty - (float)(k - 1));
        xx[k] = min(max(xi + k - 1, 0), WW - 1);
        yy[k] = min(max(yi + k - 1, 0), HH - 1);
    }
    Iw[0] = 0.f; Iw[1] = 0.f; Iw[2] = 0.f;
#pragma unroll
    for (int j = 0; j < 4; j++) {
        const float* row = Ib + yy[j] * (WW * 3);
        float r0 = 0.f, r1 = 0.f, r2 = 0.f;
#pragma unroll
        for (int k = 0; k < 4; k++) {
            const float* q = row + xx[k] * 3;
            r0 = fmaf(wx[k], q[0], r0); r1 = fmaf(wx[k], q[1], r1); r2 = fmaf(wx[k], q[2], r2);
        }
        Iw[0] = fmaf(wyv[j], r0, Iw[0]);
        Iw[1] = fmaf(wyv[j], r1, Iw[1]);
        Iw[2] = fmaf(wyv[j], r2, Iw[2]);
    }
}

// LDS bicubic from float4-padded staged tile (identical fma order)
__device__ __forceinline__ void bicubic3_lds(const lf4* __restrict__ T, int ssx, int ssy,
                                             float tx, float ty, float Iw[3]) {
    float wx[4], wyv[4];
#pragma unroll
    for (int k = 0; k < 4; k++) { wx[k] = cubicw(tx - (float)(k - 1)); wyv[k] = cubicw(ty - (float)(k - 1)); }
    Iw[0] = 0.f; Iw[1] = 0.f; Iw[2] = 0.f;
    const lf4* bp = T + (ssy - 1) * PITCH2 + (ssx - 1);
#pragma unroll
    for (int j = 0; j < 4; j++) {
        lf4 t0 = bp[j * PITCH2 + 0], t1 = bp[j * PITCH2 + 1], t2 = bp[j * PITCH2 + 2], t3 = bp[j * PITCH2 + 3];
        float r0 = fmaf(wx[0], t0.x, 0.f); r0 = fmaf(wx[1], t1.x, r0); r0 = fmaf(wx[2], t2.x, r0); r0 = fmaf(wx[3], t3.x, r0);
        float r1 = fmaf(wx[0], t0.y, 0.f); r1 = fmaf(wx[1], t1.y, r1); r1 = fmaf(wx[2], t2.y, r1); r1 = fmaf(wx[3], t3.y, r1);
        float r2 = fmaf(wx[0], t0.z, 0.f); r2 = fmaf(wx[1], t1.z, r2); r2 = fmaf(wx[2], t2.z, r2); r2 = fmaf(wx[3], t3.z, r2);
        Iw[0] = fmaf(wyv[j], r0, Iw[0]);
        Iw[1] = fmaf(wyv[j], r1, Iw[1]);
        Iw[2] = fmaf(wyv[j], r2, Iw[2]);
    }
}

extern "C" __global__ __launch_bounds__(256)
void k_init(const float* __restrict__ p0, double* __restrict__ p_store,
            int* __restrict__ done0, double* __restrict__ S_all,
            double* __restrict__ Sf, int* __restrict__ cnt) {
    int tid = threadIdx.x;
    for (int i = tid; i < MAXIT * BB * NACC; i += 256) S_all[i] = 0.0;
    if (tid < MAXIT) cnt[tid] = 0;
    if (tid < 2 * BB) Sf[tid] = 0.0;
    if (tid < BB * NPAR) p_store[tid] = (double)p0[tid];
    if (tid < BB) done0[tid] = 0;
}

// One fused iteration: 2D-tiled LDS-staged warp+reduce, last block solves.
extern "C" __global__ __launch_bounds__(384)
void k_iter(const float* __restrict__ I1, const float* __restrict__ I2,
            const double* __restrict__ p_in, const int* __restrict__ done_in,
            double* __restrict__ S, double* __restrict__ p_out,
            int* __restrict__ done_out, int* __restrict__ cnt) {
    __shared__ lf4 SMEM[6 * PITCH2 + 5 * PITCH1];     // 24704 B; aliased by solver
    __shared__ double wacc[6][NACC];
    __shared__ double S8s[BB * NACC];
    __shared__ int isLast;

    const int tid = threadIdx.x;
    const int b = blockIdx.y;
    const bool active = (done_in[b] == 0);

    if (active) {
        const int tix = blockIdx.x;             // 0..365
        const int rt = tix / 3, win = tix - rt * 3;
        const int y0 = 10 + rt * 3;
        const int x0 = 10 + win * 128;
        const int W = (win == 2) ? 108 : 128;
        const int WS2c = W + 12;
        const int sx0 = x0 - 6;

        const double* p = p_in + b * NPAR;
        const double M00 = 1.0 + p[2], M01 = p[3], M02 = p[0];
        const double M10 = p[4], M11 = 1.0 + p[5], M12 = p[1];
        const float* I1b = I1 + (size_t)b * HWPIX * 3;
        const float* I2b = I2 + (size_t)b * HWPIX * 3;

        const double ygc = M10 * (double)(x0 + 64) + M11 * (double)(y0 + 1) + M12;
        const int r0 = (int)floor(ygc) - 2;     // staged I2 rows r0..r0+5

        lf4* I2S = SMEM;
        lf4* I1S = SMEM + 6 * PITCH2;

        // stage I2 (clamped; clamp never binds here but harmless)
        for (int i = tid; i < 6 * WS2c; i += 384) {
            const int r = i / WS2c, c = i - r * WS2c;
            const int gr = min(max(r0 + r, 0), HH - 1);
            const int gc = min(max(sx0 + c, 0), WW - 1);
            const float* src = I2b + (gr * WW + gc) * 3;
            f2v ab = *(const f2v*)src;
            I2S[r * PITCH2 + c] = (lf4){ab.x, ab.y, src[2], 0.f};
        }
        // stage I1 rows y0-1..y0+3, cols x0-1..x0+W (always in-bounds)
        const int W1 = W + 2;
        for (int i = tid; i < 5 * W1; i += 384) {
            const int r = i / W1, c = i - r * W1;
            const float* src = I1b + ((y0 - 1 + r) * WW + (x0 - 1 + c)) * 3;
            f2v ab = *(const f2v*)src;
            I1S[r * PITCH1 + c] = (lf4){ab.x, ab.y, src[2], 0.f};
        }
        __syncthreads();

        const int row = tid >> 7;               // 0..2
        const int col = tid & 127;              // 0..127
        const int y = y0 + row;
        const int x = x0 + col;
        const bool lanev = (col < W) && (y < HH - DEL);
        const double X = (double)x, Y = (double)y;
        const double xg = fma(M00, X, fma(M01, Y, M02));
        const double yg = fma(M10, X, fma(M11, Y, M12));
        const double gx = rint(xg), gy = rint(yg);
        const bool ok = lanev &&
                        (gx >= (double)DEL && gx <= (double)(WW - DEL) &&
                         gy >= (double)DEL && gy <= (double)(HH - DEL));
        const double fx = floor(xg), fy = floor(yg);
        const int xi = (int)fx, yi = (int)fy;
        const float tx = (float)(xg - fx), ty = (float)(yg - fy);
        const int sxi = xi - sx0, syi = yi - r0;
        const bool inwin = ok && (sxi >= 1) && (sxi <= WS2c - 3) && (syi >= 1) && (syi <= 3);

        float Iw[3];
        if (ok && !inwin) {
            bicubic3_fast(I2b, xg, yg, Iw);     // rare drift fallback
        } else {
            const int ssx = inwin ? sxi : 8;
            const int ssy = inwin ? syi : 2;
            bicubic3_lds(I2S, ssx, ssy, tx, ty, Iw);
        }

        const int rI = row + 1;
        const int cI = min(col + 1, W);         // clamp so invalid lanes read staged data
        const lf4 cc  = I1S[rI * PITCH1 + cI];
        const lf4 cl4 = I1S[rI * PITCH1 + cI - 1];
        const lf4 cr4 = I1S[rI * PITCH1 + cI + 1];
        const lf4 cu4 = I1S[(rI - 1) * PITCH1 + cI];
        const lf4 cd4 = I1S[(rI + 1) * PITCH1 + cI];
        const float cv[3] = {cc.x, cc.y, cc.z};
        const float cl[3] = {cl4.x, cl4.y, cl4.z};
        const float cr[3] = {cr4.x, cr4.y, cr4.z};
        const float cu[3] = {cu4.x, cu4.y, cu4.z};
        const float cd[3] = {cd4.x, cd4.y, cd4.z};

        const float msk = ok ? 1.0f : 0.0f;
        float Af = 0.f, Bf = 0.f, Cf = 0.f, T0f = 0.f, T1f = 0.f;
#pragma unroll
        for (int ch = 0; ch < 3; ch++) {
            const float Ix = (cr[ch] - cl[ch]) * 0.5f;
            const float Iy = (cd[ch] - cu[ch]) * 0.5f;
            const float d = Iw[ch] - cv[ch];
            const float u = d * 20.0f;
            const float w = msk / sqrtf(fmaf(u, u, 1.0f));
            const float wd = w * d;
            T0f = fmaf(Ix, wd, T0f);
            T1f = fmaf(Iy, wd, T1f);
            const float wIx = w * Ix;
            Af = fmaf(wIx, Ix, Af);
            Bf = fmaf(wIx, Iy, Bf);
            Cf = fmaf(w * Iy, Iy, Cf);
        }
        double s[13];
        {
            const double T0 = (double)T0f, T1 = (double)T1f;
            const double A = (double)Af, Bd = (double)Bf, Cd = (double)Cf;
            const double XX = X * X;
            s[0] = T0;  s[1] = T0 * X;
            s[2] = T1;  s[3] = T1 * X;
            s[4] = A;   s[5] = A * X;   s[6] = A * XX;
            s[7] = Bd;  s[8] = Bd * X;  s[9] = Bd * XX;
            s[10] = Cd; s[11] = Cd * X; s[12] = Cd * XX;
        }
#pragma unroll
        for (int i = 0; i < 13; i++) {
            double v = s[i];
#pragma unroll
            for (int off = 32; off >= 1; off >>= 1) v += __shfl_down(v, off, 64);
            s[i] = v;
        }
        const int wid = tid >> 6, lane = tid & 63;
        if (lane == 0) {
            const double Yw = (double)(y0 + (wid >> 1));
            const double YY = Yw * Yw;
            double* o = wacc[wid];
            o[0] = s[0];  o[1] = s[1];  o[2] = s[0] * Yw;
            o[3] = s[2];  o[4] = s[3];  o[5] = s[2] * Yw;
            o[6] = s[4];  o[7] = s[5];  o[8] = s[4] * Yw;
            o[9] = s[6];  o[10] = s[5] * Yw;  o[11] = s[4] * YY;
            o[12] = s[7]; o[13] = s[8]; o[14] = s[7] * Yw;
            o[15] = s[9]; o[16] = s[8] * Yw;  o[17] = s[7] * YY;
            o[18] = s[10]; o[19] = s[11]; o[20] = s[10] * Yw;
            o[21] = s[12]; o[22] = s[11] * Yw; o[23] = s[10] * YY;
        }
        __syncthreads();
        if (tid < NACC) {
            double v = wacc[0][tid] + wacc[1][tid] + wacc[2][tid] +
                       wacc[3][tid] + wacc[4][tid] + wacc[5][tid];
            unsafeAtomicAdd(&S[b * NACC + tid], v);
        }
    }

    // ---- last-block-does-solve epilogue (ALL blocks participate) ----
    __syncthreads();
    if (tid == 0) {
        __threadfence();
        int old = __hip_atomic_fetch_add(cnt, 1, __ATOMIC_ACQ_REL, __HIP_MEMORY_SCOPE_AGENT);
        isLast = (old == GRID_ITER - 1) ? 1 : 0;
    }
    __syncthreads();
    if (!isLast) return;

    __threadfence();
    if (tid < BB * NACC)
        S8s[tid] = __hip_atomic_load(&S[tid], __ATOMIC_RELAXED, __HIP_MEMORY_SCOPE_AGENT);
    __syncthreads();
    if (tid >= BB) return;
    {
        const int bb = tid;
        if (done_in[bb]) {
            done_out[bb] = 1;
            for (int i = 0; i < NPAR; i++) p_out[bb * NPAR + i] = p_in[bb * NPAR + i];
            return;
        }
        const double* Sb = S8s + bb * NACC;
        double bv[6] = {Sb[0], Sb[3], Sb[1], Sb[2], Sb[4], Sb[5]};
        double Hm[6][6];
        Hm[0][0] = Sb[6];  Hm[0][1] = Sb[12]; Hm[0][2] = Sb[7];  Hm[0][3] = Sb[8];  Hm[0][4] = Sb[13]; Hm[0][5] = Sb[14];
        Hm[1][1] = Sb[18]; Hm[1][2] = Sb[13]; Hm[1][3] = Sb[14]; Hm[1][4] = Sb[19]; Hm[1][5] = Sb[20];
        Hm[2][2] = Sb[9];  Hm[2][3] = Sb[10]; Hm[2][4] = Sb[15]; Hm[2][5] = Sb[16];
        Hm[3][3] = Sb[11]; Hm[3][4] = Sb[16]; Hm[3][5] = Sb[17];
        Hm[4][4] = Sb[21]; Hm[4][5] = Sb[22];
        Hm[5][5] = Sb[23];
        for (int i = 0; i < 6; i++)
            for (int jj = 0; jj < i; jj++) Hm[i][jj] = Hm[jj][i];
        for (int i = 0; i < 6; i++) Hm[i][i] += 1e-6;

        // 6x6 solve in LDS (alias SMEM; compute phase fully done)
        double* Aa = (double*)SMEM + tid * 48;   // 6 rows x 8 stride
        for (int i = 0; i < 6; i++) {
            for (int jj = 0; jj < 6; jj++) Aa[i * 8 + jj] = Hm[i][jj];
            Aa[i * 8 + 6] = bv[i];
        }
        for (int k = 0; k < 6; k++) {
            int piv = k;
            double mx = fabs(Aa[k * 8 + k]);
            for (int r = k + 1; r < 6; r++) {
                double v = fabs(Aa[r * 8 + k]);
                if (v > mx) { mx = v; piv = r; }
            }
            if (piv != k)
                for (int jj = k; jj < 7; jj++) { double t = Aa[k * 8 + jj]; Aa[k * 8 + jj] = Aa[piv * 8 + jj]; Aa[piv * 8 + jj] = t; }
            const double inv = 1.0 / Aa[k * 8 + k];
            for (int r = k + 1; r < 6; r++) {
                const double f = Aa[r * 8 + k] * inv;
                for (int jj = k; jj < 7; jj++) Aa[r * 8 + jj] -= f * Aa[k * 8 + jj];
            }
        }
        double dp[6];
        for (int i = 5; i >= 0; i--) {
            double sv = Aa[i * 8 + 6];
            for (int jj = i + 1; jj < 6; jj++) sv -= Aa[i * 8 + jj] * dp[jj];
            dp[i] = sv / Aa[i * 8 + i];
        }
        const double nrm = sqrt(dp[0]*dp[0] + dp[1]*dp[1] + dp[2]*dp[2] + dp[3]*dp[3] + dp[4]*dp[4] + dp[5]*dp[5]);
        const int conv = (nrm < 1e-3) ? 1 : 0;

        const double* pc = p_in + bb * NPAR;
        const double m00 = 1.0 + pc[2], m01 = pc[3], m02 = pc[0];
        const double m10 = pc[4], m11 = 1.0 + pc[5], m12 = pc[1];
        const double q00 = 1.0 + dp[2], q01 = dp[3], q02 = dp[0];
        const double q10 = dp[4], q11 = 1.0 + dp[5], q12 = dp[1];
        const double det = q00 * q11 - q01 * q10;
        const double i00 = q11 / det, i01 = -q01 / det;
        const double i10 = -q10 / det, i11 = q00 / det;
        const double it0 = -(i00 * q02 + i01 * q12);
        const double it1 = -(i10 * q02 + i11 * q12);
        const double n00 = m00 * i00 + m01 * i10;
        const double n01 = m00 * i01 + m01 * i11;
        const double n02 = m00 * it0 + m01 * it1 + m02;
        const double n10 = m10 * i00 + m11 * i10;
        const double n11 = m10 * i01 + m11 * i11;
        const double n12 = m10 * it0 + m11 * it1 + m12;
        p_out[bb * NPAR + 0] = n02;
        p_out[bb * NPAR + 1] = n12;
        p_out[bb * NPAR + 2] = n00 - 1.0;
        p_out[bb * NPAR + 3] = n01;
        p_out[bb * NPAR + 4] = n10;
        p_out[bb * NPAR + 5] = n11 - 1.0;
        done_out[bb] = conv;
    }
}

extern "C" __global__ __launch_bounds__(384)
void k_final_map(const float* __restrict__ I1, const float* __restrict__ I2,
                 const double* __restrict__ p_fin, float* __restrict__ DI_out,
                 float* __restrict__ Iw_out, double* __restrict__ Sf) {
    __shared__ lf4 I2S[6 * PITCH2];
    __shared__ double wsum[6][2];
    const int tid = threadIdx.x;
    const int b = blockIdx.y;
    const int tix = blockIdx.x;                 // 0..383
    const int rt = tix / 3, win = tix - rt * 3;
    const int y0 = rt * 3;
    const int x0 = win * 128;
    const int WS2c = 140;
    const int sx0 = x0 - 6;

    const double* p = p_fin + b * NPAR;
    const double M00 = 1.0 + p[2], M01 = p[3], M02 = p[0];
    const double M10 = p[4], M11 = 1.0 + p[5], M12 = p[1];
    const float* I1b = I1 + (size_t)b * HWPIX * 3;
    const float* I2b = I2 + (size_t)b * HWPIX * 3;
    float* DIb = DI_out + (size_t)b * HWPIX * 3;
    float* Iwb = Iw_out + (size_t)b * HWPIX * 3;

    const double ygc = M10 * (double)(x0 + 64) + M11 * (double)(y0 + 1) + M12;
    const int r0 = (int)floor(ygc) - 2;

    for (int i = tid; i < 6 * WS2c; i += 384) {
        const int r = i / WS2c, c = i - r * WS2c;
        const int gr = min(max(r0 + r, 0), HH - 1);    // clamping == reference clip
        const int gc = min(max(sx0 + c, 0), WW - 1);
        const float* src = I2b + (gr * WW + gc) * 3;
        f2v ab = *(const f2v*)src;
        I2S[r * PITCH2 + c] = (lf4){ab.x, ab.y, src[2], 0.f};
    }
    __syncthreads();

    const int row = tid >> 7, col = tid & 127;
    const int y = y0 + row, x = x0 + col;
    const int pix = y * WW + x;
    const double X = (double)x, Y = (double)y;
    const double xg = fma(M00, X, fma(M01, Y, M02));
    const double yg = fma(M10, X, fma(M11, Y, M12));
    const double fx = floor(xg), fy = floor(yg);
    const int xi = (int)fx, yi = (int)fy;
    const float tx = (float)(xg - fx), ty = (float)(yg - fy);
    const int sxi = xi - sx0, syi = yi - r0;
    const bool inwin = (sxi >= 1) && (sxi <= WS2c - 3) && (syi >= 1) && (syi <= 3);

    float Iw[3];
    if (inwin) bicubic3_lds(I2S, sxi, syi, tx, ty, Iw);
    else       bicubic3_gen(I2b, xg, yg, Iw);

    Iwb[pix * 3 + 0] = Iw[0];
    Iwb[pix * 3 + 1] = Iw[1];
    Iwb[pix * 3 + 2] = Iw[2];

    const bool v1 = (x >= DEL) && (x < WW - DEL) && (y >= DEL) && (y < HH - DEL);
    const double gx = rint(xg), gy = rint(yg);
    const bool wm = (gx >= (double)DEL && gx <= (double)(WW - DEL) &&
                     gy >= (double)DEL && gy <= (double)(HH - DEL));
    const bool m = v1 && wm;

    double rho_s = 0.0, cnt_s = 0.0;
    const float* c = I1b + pix * 3;
    if (m) {
#pragma unroll
        for (int ch = 0; ch < 3; ch++) {
            const float d = Iw[ch] - c[ch];
            DIb[pix * 3 + ch] = d;
            const float u = d * 20.0f;
            const float rho = 0.005f * (sqrtf(fmaf(u, u, 1.0f)) - 1.0f);
            rho_s += (double)rho;
        }
        cnt_s = 3.0;
    } else {
        DIb[pix * 3 + 0] = 0.0f;
        DIb[pix * 3 + 1] = 0.0f;
        DIb[pix * 3 + 2] = 0.0f;
    }
#pragma unroll
    for (int off = 32; off >= 1; off >>= 1) {
        rho_s += __shfl_down(rho_s, off, 64);
        cnt_s += __shfl_down(cnt_s, off, 64);
    }
    const int wid = tid >> 6, lane = tid & 63;
    if (lane == 0) { wsum[wid][0] = rho_s; wsum[wid][1] = cnt_s; }
    __syncthreads();
    if (tid < 2) {
        double sv = wsum[0][tid] + wsum[1][tid] + wsum[2][tid] +
                    wsum[3][tid] + wsum[4][tid] + wsum[5][tid];
        unsafeAtomicAdd(&Sf[b * 2 + tid], sv);
    }
}

extern "C" __global__ void k_finish(const double* __restrict__ p_fin,
                                    const double* __restrict__ Sf,
                                    float* __restrict__ out) {
    const int tid = threadIdx.x;  // 64 threads
    if (tid < BB * NPAR) out[tid] = (float)p_fin[tid];           // pf
    if (tid >= 48 && tid < 48 + BB) {
        const int b = tid - 48;
        out[48 + b] = (float)(Sf[b * 2 + 0] / fmax(Sf[b * 2 + 1], 1.0));  // err
    }
}

extern "C" void kernel_launch(void* const* d_in, const int* in_sizes, int n_in,
                              void* d_out, int out_size, void* d_ws, size_t ws_size,
                              hipStream_t stream) {
    const float* I1 = (const float*)d_in[0];
    const float* I2 = (const float*)d_in[1];
    const float* p0 = (const float*)d_in[2];
    float* out = (float*)d_out;

    // ws layout (8B-aligned):
    // [0)      p_store (MAXIT+1)*48 doubles = 4992 B
    // [4992)   done    (MAXIT+1)*8 ints     = 416 B
    // [5408)   S_all   MAXIT*8*24 doubles   = 18432 B
    // [23840)  Sf      16 doubles           = 128 B
    // [23968)  cnt     MAXIT ints           = 48 B
    double* p_store = (double*)d_ws;
    int* done_flags = (int*)((char*)d_ws + 4992);
    double* S_all = (double*)((char*)d_ws + 5408);
    double* Sf = (double*)((char*)d_ws + 23840);
    int* cnt = (int*)((char*)d_ws + 23968);

    k_init<<<1, 256, 0, stream>>>(p0, p_store, done_flags, S_all, Sf, cnt);
    dim3 gridI(NRT * 3, BB), blkI(384);
    for (int it = 0; it < MAXIT; it++) {
        k_iter<<<gridI, blkI, 0, stream>>>(I1, I2,
                                           p_store + (size_t)it * BB * NPAR,
                                           done_flags + it * BB,
                                           S_all + (size_t)it * BB * NACC,
                                           p_store + (size_t)(it + 1) * BB * NPAR,
                                           done_flags + (it + 1) * BB,
                                           cnt + it);
    }
    float* DI_out = out + 56;
    float* Iw_out = out + 56 + (size_t)BB * HWPIX * 3;
    dim3 gridF(128 * 3, BB), blkF(384);
    k_final_map<<<gridF, blkF, 0, stream>>>(I1, I2, p_store + (size_t)MAXIT * BB * NPAR,
                                            DI_out, Iw_out, Sf);
    k_finish<<<1, 64, 0, stream>>>(p_store + (size_t)MAXIT * BB * NPAR, Sf, out);
}

// Round 6
// 694.722 us; speedup vs baseline: 2.7852x; 2.7852x over previous
//
#include <hip/hip_runtime.h>
#include <math.h>

#define BB 8
#define HH 384
#define WW 384
#define NPAR 6
#define DEL 10
#define MAXIT 12
#define NACC 24
#define HWPIX (HH*WW)
#define NRT6 61                 // 6-row tiles covering rows 10..373 (last partial)
#define PITCH2 141              // LDS pitch (float4) for I2 stage (cols <= 140)
#define PITCH1 131              // LDS pitch (float4) for I1 stage (cols <= 130)
#define NR2 10                  // staged I2 rows in k_iter

typedef float vf4 __attribute__((ext_vector_type(4)));
typedef vf4 uvf4 __attribute__((aligned(4)));      // 4B-aligned global dwordx4
typedef float f2v __attribute__((ext_vector_type(2), aligned(4)));
typedef float lf4 __attribute__((ext_vector_type(4)));  // 16B-aligned (LDS)

__device__ __forceinline__ vf4 ldv4(const float* p) { return *(const uvf4*)p; }

__device__ __forceinline__ float cubicw(float s) {
    s = fabsf(s);
    float s2 = s * s, s3 = s2 * s;
    float w1 = 1.5f * s3 - 2.5f * s2 + 1.0f;
    float w2 = -0.5f * s3 + 2.5f * s2 - 4.0f * s + 2.0f;
    return (s <= 1.0f) ? w1 : ((s < 2.0f) ? w2 : 0.0f);
}

// global fast-path bicubic (taps guaranteed in-bounds; drift fallback)
__device__ __forceinline__ void bicubic3_fast(const float* __restrict__ Ib, double xg, double yg, float Iw[3]) {
    double fx = floor(xg), fy = floor(yg);
    float tx = (float)(xg - fx), ty = (float)(yg - fy);
    int xi = (int)fx, yi = (int)fy;
    float wx[4], wyv[4];
#pragma unroll
    for (int k = 0; k < 4; k++) { wx[k] = cubicw(tx - (float)(k - 1)); wyv[k] = cubicw(ty - (float)(k - 1)); }
    Iw[0] = 0.f; Iw[1] = 0.f; Iw[2] = 0.f;
    const float* base = Ib + (yi - 1) * (WW * 3) + (xi - 1) * 3;
#pragma unroll
    for (int j = 0; j < 4; j++) {
        const float* r = base + j * (WW * 3);
        vf4 v0 = ldv4(r), v1 = ldv4(r + 4), v2 = ldv4(r + 8);
        float r0 = fmaf(wx[0], v0.x, 0.f); r0 = fmaf(wx[1], v0.w, r0); r0 = fmaf(wx[2], v1.z, r0); r0 = fmaf(wx[3], v2.y, r0);
        float r1 = fmaf(wx[0], v0.y, 0.f); r1 = fmaf(wx[1], v1.x, r1); r1 = fmaf(wx[2], v1.w, r1); r1 = fmaf(wx[3], v2.z, r1);
        float r2 = fmaf(wx[0], v0.z, 0.f); r2 = fmaf(wx[1], v1.y, r2); r2 = fmaf(wx[2], v2.x, r2); r2 = fmaf(wx[3], v2.w, r2);
        Iw[0] = fmaf(wyv[j], r0, Iw[0]);
        Iw[1] = fmaf(wyv[j], r1, Iw[1]);
        Iw[2] = fmaf(wyv[j], r2, Iw[2]);
    }
}

// general bicubic with clip-to-edge (k_final_map fallback)
__device__ __forceinline__ void bicubic3_gen(const float* __restrict__ Ib, double xg, double yg, float Iw[3]) {
    double fx = floor(xg), fy = floor(yg);
    int xi = (int)fx, yi = (int)fy;
    float tx = (float)(xg - fx), ty = (float)(yg - fy);
    float wx[4], wyv[4];
    int xx[4], yy[4];
#pragma unroll
    for (int k = 0; k < 4; k++) {
        wx[k] = cubicw(tx - (float)(k - 1)); wyv[k] = cubicw(ty - (float)(k - 1));
        xx[k] = min(max(xi + k - 1, 0), WW - 1);
        yy[k] = min(max(yi + k - 1, 0), HH - 1);
    }
    Iw[0] = 0.f; Iw[1] = 0.f; Iw[2] = 0.f;
#pragma unroll
    for (int j = 0; j < 4; j++) {
        const float* row = Ib + yy[j] * (WW * 3);
        float r0 = 0.f, r1 = 0.f, r2 = 0.f;
#pragma unroll
        for (int k = 0; k < 4; k++) {
            const float* q = row + xx[k] * 3;
            r0 = fmaf(wx[k], q[0], r0); r1 = fmaf(wx[k], q[1], r1); r2 = fmaf(wx[k], q[2], r2);
        }
        Iw[0] = fmaf(wyv[j], r0, Iw[0]);
        Iw[1] = fmaf(wyv[j], r1, Iw[1]);
        Iw[2] = fmaf(wyv[j], r2, Iw[2]);
    }
}

// LDS bicubic from float4-padded staged tile (identical fma order)
__device__ __forceinline__ void bicubic3_lds(const lf4* __restrict__ T, int ssx, int ssy,
                                             float tx, float ty, float Iw[3]) {
    float wx[4], wyv[4];
#pragma unroll
    for (int k = 0; k < 4; k++) { wx[k] = cubicw(tx - (float)(k - 1)); wyv[k] = cubicw(ty - (float)(k - 1)); }
    Iw[0] = 0.f; Iw[1] = 0.f; Iw[2] = 0.f;
    const lf4* bp = T + (ssy - 1) * PITCH2 + (ssx - 1);
#pragma unroll
    for (int j = 0; j < 4; j++) {
        lf4 t0 = bp[j * PITCH2 + 0], t1 = bp[j * PITCH2 + 1], t2 = bp[j * PITCH2 + 2], t3 = bp[j * PITCH2 + 3];
        float r0 = fmaf(wx[0], t0.x, 0.f); r0 = fmaf(wx[1], t1.x, r0); r0 = fmaf(wx[2], t2.x, r0); r0 = fmaf(wx[3], t3.x, r0);
        float r1 = fmaf(wx[0], t0.y, 0.f); r1 = fmaf(wx[1], t1.y, r1); r1 = fmaf(wx[2], t2.y, r1); r1 = fmaf(wx[3], t3.y, r1);
        float r2 = fmaf(wx[0], t0.z, 0.f); r2 = fmaf(wx[1], t1.z, r2); r2 = fmaf(wx[2], t2.z, r2); r2 = fmaf(wx[3], t3.z, r2);
        Iw[0] = fmaf(wyv[j], r0, Iw[0]);
        Iw[1] = fmaf(wyv[j], r1, Iw[1]);
        Iw[2] = fmaf(wyv[j], r2, Iw[2]);
    }
}

extern "C" __global__ __launch_bounds__(256)
void k_init(const float* __restrict__ p0, double* __restrict__ p_store,
            int* __restrict__ done0, double* __restrict__ S_all,
            double* __restrict__ Sf) {
    int tid = threadIdx.x;
    for (int i = tid; i < MAXIT * BB * NACC; i += 256) S_all[i] = 0.0;
    if (tid < 2 * BB) Sf[tid] = 0.0;
    if (tid < BB * NPAR) p_store[tid] = (double)p0[tid];
    if (tid < BB) done0[tid] = 0;
}

// 6-row x 128-col tile; wave w owns row y0+w (2 px/lane). LDS-staged I1/I2.
extern "C" __global__ __launch_bounds__(384)
void k_iter(const float* __restrict__ I1, const float* __restrict__ I2,
            const double* __restrict__ p_in, const int* __restrict__ done_in,
            double* __restrict__ S) {
    __shared__ lf4 SMEM[NR2 * PITCH2 + 8 * PITCH1];   // 40448 B
    __shared__ double wacc[6][NACC];

    const int b = blockIdx.y;
    if (done_in[b]) return;                 // frozen batch: S stays zero
    const int tid = threadIdx.x;
    const int tix = blockIdx.x;             // 0..182
    const int rt = tix / 3, win = tix - rt * 3;
    const int y0 = 10 + rt * 6;
    const int x0 = 10 + win * 128;
    const int W = (win == 2) ? 108 : 128;
    const int WS2c = W + 12;
    const int sx0 = x0 - 6;

    const double* p = p_in + b * NPAR;
    const double M00 = 1.0 + p[2], M01 = p[3], M02 = p[0];
    const double M10 = p[4], M11 = 1.0 + p[5], M12 = p[1];
    const float* I1b = I1 + (size_t)b * HWPIX * 3;
    const float* I2b = I2 + (size_t)b * HWPIX * 3;

    const double ygc = M10 * (double)(x0 + 64) + M11 * ((double)y0 + 2.5) + M12;
    const int r0 = (int)floor(ygc) - 4;     // staged I2 rows r0..r0+9

    lf4* I2S = SMEM;
    lf4* I1S = SMEM + NR2 * PITCH2;

    // stage I2 (row clamp for drift safety; cols always in-bounds)
    for (int i = tid; i < NR2 * WS2c; i += 384) {
        const int r = i / WS2c, c = i - r * WS2c;
        const int gr = min(max(r0 + r, 0), HH - 1);
        const float* src = I2b + (gr * WW + sx0 + c) * 3;
        f2v ab = *(const f2v*)src;
        I2S[r * PITCH2 + c] = (lf4){ab.x, ab.y, src[2], 0.f};
    }
    // stage I1 rows y0-1..y0+6 (always in-bounds: 9..377)
    const int W1 = W + 2;
    for (int i = tid; i < 8 * W1; i += 384) {
        const int r = i / W1, c = i - r * W1;
        const float* src = I1b + ((y0 - 1 + r) * WW + (x0 - 1 + c)) * 3;
        f2v ab = *(const f2v*)src;
        I1S[r * PITCH1 + c] = (lf4){ab.x, ab.y, src[2], 0.f};
    }
    __syncthreads();

    const int wid = tid >> 6, lane = tid & 63;
    const int y = y0 + wid;                 // wave-uniform row
    const bool rowv = (y < HH - DEL);
    const double Y = (double)y;
    const double Bx = M01 * Y + M02;
    const double By = M11 * Y + M12;

    double s[13];
#pragma unroll
    for (int i = 0; i < 13; i++) s[i] = 0.0;
    // s: 0=T0 1=T0X 2=T1 3=T1X 4=A 5=AX 6=AXX 7=B 8=BX 9=BXX 10=C 11=CX 12=CXX

#pragma unroll
    for (int step = 0; step < 2; step++) {
        const int col = lane + 64 * step;
        const int x = x0 + col;
        const double X = (double)x;
        const double xg = fma(M00, X, Bx);
        const double yg = fma(M10, X, By);
        const double gx = rint(xg), gy = rint(yg);   // half-to-even like jnp.round
        const bool ok = rowv && (col < W) &&
                        (gx >= (double)DEL && gx <= (double)(WW - DEL) &&
                         gy >= (double)DEL && gy <= (double)(HH - DEL));
        const double fx = floor(xg), fy = floor(yg);
        const int xi = (int)fx, yi = (int)fy;
        const float tx = (float)(xg - fx), ty = (float)(yg - fy);
        const int sxi = xi - sx0, syi = yi - r0;
        const bool inwin = ok && (sxi >= 1) && (sxi <= WS2c - 3) && (syi >= 1) && (syi <= NR2 - 3);

        float Iw[3];
        if (ok && !inwin) {
            bicubic3_fast(I2b, xg, yg, Iw);   // rare drift fallback
        } else {
            const int ssx = inwin ? sxi : 8;
            const int ssy = inwin ? syi : 2;
            bicubic3_lds(I2S, ssx, ssy, tx, ty, Iw);
        }

        const int rI = wid + 1;
        const int cI = min(col + 1, W);       // clamp: invalid lanes read staged data
        const lf4 cc  = I1S[rI * PITCH1 + cI];
        const lf4 cl4 = I1S[rI * PITCH1 + cI - 1];
        const lf4 cr4 = I1S[rI * PITCH1 + cI + 1];
        const lf4 cu4 = I1S[(rI - 1) * PITCH1 + cI];
        const lf4 cd4 = I1S[(rI + 1) * PITCH1 + cI];
        const float cv[3] = {cc.x, cc.y, cc.z};
        const float cl[3] = {cl4.x, cl4.y, cl4.z};
        const float cr[3] = {cr4.x, cr4.y, cr4.z};
        const float cu[3] = {cu4.x, cu4.y, cu4.z};
        const float cd[3] = {cd4.x, cd4.y, cd4.z};

        const float msk = ok ? 1.0f : 0.0f;
        float Af = 0.f, Bf = 0.f, Cf = 0.f, T0f = 0.f, T1f = 0.f;
#pragma unroll
        for (int ch = 0; ch < 3; ch++) {
            const float Ix = (cr[ch] - cl[ch]) * 0.5f;
            const float Iy = (cd[ch] - cu[ch]) * 0.5f;
            const float d = Iw[ch] - cv[ch];
            const float u = d * 20.0f;
            const float w = msk / sqrtf(fmaf(u, u, 1.0f));
            const float wd = w * d;
            T0f = fmaf(Ix, wd, T0f);
            T1f = fmaf(Iy, wd, T1f);
            const float wIx = w * Ix;
            Af = fmaf(wIx, Ix, Af);
            Bf = fmaf(wIx, Iy, Bf);
            Cf = fmaf(w * Iy, Iy, Cf);
        }
        const double T0 = (double)T0f, T1 = (double)T1f;
        const double A = (double)Af, Bd = (double)Bf, Cd = (double)Cf;
        const double XX = X * X;
        s[0] += T0;  s[1] = fma(T0, X, s[1]);
        s[2] += T1;  s[3] = fma(T1, X, s[3]);
        s[4] += A;   s[5] = fma(A, X, s[5]);   s[6] = fma(A, XX, s[6]);
        s[7] += Bd;  s[8] = fma(Bd, X, s[8]);  s[9] = fma(Bd, XX, s[9]);
        s[10] += Cd; s[11] = fma(Cd, X, s[11]); s[12] = fma(Cd, XX, s[12]);
    }

    // wave shuffle reduce of the 13 sums (amortized over 2 px/lane)
#pragma unroll
    for (int i = 0; i < 13; i++) {
        double v = s[i];
#pragma unroll
        for (int off = 32; off >= 1; off >>= 1) v += __shfl_down(v, off, 64);
        s[i] = v;
    }
    if (lane == 0) {
        const double YY = Y * Y;
        double* o = wacc[wid];
        o[0] = s[0];  o[1] = s[1];  o[2] = s[0] * Y;
        o[3] = s[2];  o[4] = s[3];  o[5] = s[2] * Y;
        o[6] = s[4];  o[7] = s[5];  o[8] = s[4] * Y;
        o[9] = s[6];  o[10] = s[5] * Y;  o[11] = s[4] * YY;
        o[12] = s[7]; o[13] = s[8]; o[14] = s[7] * Y;
        o[15] = s[9]; o[16] = s[8] * Y;  o[17] = s[7] * YY;
        o[18] = s[10]; o[19] = s[11]; o[20] = s[10] * Y;
        o[21] = s[12]; o[22] = s[11] * Y; o[23] = s[10] * YY;
    }
    __syncthreads();
    if (tid < NACC) {
        double v = wacc[0][tid] + wacc[1][tid] + wacc[2][tid] +
                   wacc[3][tid] + wacc[4][tid] + wacc[5][tid];
        unsafeAtomicAdd(&S[b * NACC + tid], v);   // hw f64 atomic; order noise ~1e-15
    }
}

extern "C" __global__ __launch_bounds__(256)
void k_solve(const double* __restrict__ S_it, const double* __restrict__ p_in,
             const int* __restrict__ done_in, double* __restrict__ p_out,
             int* __restrict__ done_out) {
    __shared__ double S[BB][NACC];
    const int tid = threadIdx.x;
    if (tid < BB * NACC) S[tid / NACC][tid % NACC] = S_it[tid];
    __syncthreads();
    if (tid >= BB) return;
    const int b = tid;
    if (done_in[b]) {
        done_out[b] = 1;
        for (int i = 0; i < NPAR; i++) p_out[b * NPAR + i] = p_in[b * NPAR + i];
        return;
    }
    const double* Sb = S[b];
    double bv[6] = {Sb[0], Sb[3], Sb[1], Sb[2], Sb[4], Sb[5]};
    double Hm[6][6];
    Hm[0][0] = Sb[6];  Hm[0][1] = Sb[12]; Hm[0][2] = Sb[7];  Hm[0][3] = Sb[8];  Hm[0][4] = Sb[13]; Hm[0][5] = Sb[14];
    Hm[1][1] = Sb[18]; Hm[1][2] = Sb[13]; Hm[1][3] = Sb[14]; Hm[1][4] = Sb[19]; Hm[1][5] = Sb[20];
    Hm[2][2] = Sb[9];  Hm[2][3] = Sb[10]; Hm[2][4] = Sb[15]; Hm[2][5] = Sb[16];
    Hm[3][3] = Sb[11]; Hm[3][4] = Sb[16]; Hm[3][5] = Sb[17];
    Hm[4][4] = Sb[21]; Hm[4][5] = Sb[22];
    Hm[5][5] = Sb[23];
    for (int i = 0; i < 6; i++)
        for (int jj = 0; jj < i; jj++) Hm[i][jj] = Hm[jj][i];
    for (int i = 0; i < 6; i++) Hm[i][i] += 1e-6;

    double Aa[6][7];
    for (int i = 0; i < 6; i++) {
        for (int jj = 0; jj < 6; jj++) Aa[i][jj] = Hm[i][jj];
        Aa[i][6] = bv[i];
    }
    for (int k = 0; k < 6; k++) {
        int piv = k;
        double mx = fabs(Aa[k][k]);
        for (int r = k + 1; r < 6; r++) {
            double v = fabs(Aa[r][k]);
            if (v > mx) { mx = v; piv = r; }
        }
        if (piv != k)
            for (int jj = k; jj < 7; jj++) { double t = Aa[k][jj]; Aa[k][jj] = Aa[piv][jj]; Aa[piv][jj] = t; }
        const double inv = 1.0 / Aa[k][k];
        for (int r = k + 1; r < 6; r++) {
            const double f = Aa[r][k] * inv;
            for (int jj = k; jj < 7; jj++) Aa[r][jj] -= f * Aa[k][jj];
        }
    }
    double dp[6];
    for (int i = 5; i >= 0; i--) {
        double sv = Aa[i][6];
        for (int jj = i + 1; jj < 6; jj++) sv -= Aa[i][jj] * dp[jj];
        dp[i] = sv / Aa[i][i];
    }
    const double nrm = sqrt(dp[0]*dp[0] + dp[1]*dp[1] + dp[2]*dp[2] + dp[3]*dp[3] + dp[4]*dp[4] + dp[5]*dp[5]);
    const int conv = (nrm < 1e-3) ? 1 : 0;

    const double* pc = p_in + b * NPAR;
    const double m00 = 1.0 + pc[2], m01 = pc[3], m02 = pc[0];
    const double m10 = pc[4], m11 = 1.0 + pc[5], m12 = pc[1];
    const double q00 = 1.0 + dp[2], q01 = dp[3], q02 = dp[0];
    const double q10 = dp[4], q11 = 1.0 + dp[5], q12 = dp[1];
    const double det = q00 * q11 - q01 * q10;
    const double i00 = q11 / det, i01 = -q01 / det;
    const double i10 = -q10 / det, i11 = q00 / det;
    const double it0 = -(i00 * q02 + i01 * q12);
    const double it1 = -(i10 * q02 + i11 * q12);
    const double n00 = m00 * i00 + m01 * i10;
    const double n01 = m00 * i01 + m01 * i11;
    const double n02 = m00 * it0 + m01 * it1 + m02;
    const double n10 = m10 * i00 + m11 * i10;
    const double n11 = m10 * i01 + m11 * i11;
    const double n12 = m10 * it0 + m11 * it1 + m12;
    p_out[b * NPAR + 0] = n02;
    p_out[b * NPAR + 1] = n12;
    p_out[b * NPAR + 2] = n00 - 1.0;
    p_out[b * NPAR + 3] = n01;
    p_out[b * NPAR + 4] = n10;
    p_out[b * NPAR + 5] = n11 - 1.0;
    done_out[b] = conv;
}

extern "C" __global__ __launch_bounds__(384)
void k_final_map(const float* __restrict__ I1, const float* __restrict__ I2,
                 const double* __restrict__ p_fin, float* __restrict__ DI_out,
                 float* __restrict__ Iw_out, double* __restrict__ Sf) {
    __shared__ lf4 I2S[6 * PITCH2];
    __shared__ double wsum[6][2];
    const int tid = threadIdx.x;
    const int b = blockIdx.y;
    const int tix = blockIdx.x;                 // 0..383
    const int rt = tix / 3, win = tix - rt * 3;
    const int y0 = rt * 3;
    const int x0 = win * 128;
    const int WS2c = 140;
    const int sx0 = x0 - 6;

    const double* p = p_fin + b * NPAR;
    const double M00 = 1.0 + p[2], M01 = p[3], M02 = p[0];
    const double M10 = p[4], M11 = 1.0 + p[5], M12 = p[1];
    const float* I1b = I1 + (size_t)b * HWPIX * 3;
    const float* I2b = I2 + (size_t)b * HWPIX * 3;
    float* DIb = DI_out + (size_t)b * HWPIX * 3;
    float* Iwb = Iw_out + (size_t)b * HWPIX * 3;

    const double ygc = M10 * (double)(x0 + 64) + M11 * (double)(y0 + 1) + M12;
    const int r0 = (int)floor(ygc) - 2;

    for (int i = tid; i < 6 * WS2c; i += 384) {
        const int r = i / WS2c, c = i - r * WS2c;
        const int gr = min(max(r0 + r, 0), HH - 1);    // clamping == reference clip
        const int gc = min(max(sx0 + c, 0), WW - 1);
        const float* src = I2b + (gr * WW + gc) * 3;
        f2v ab = *(const f2v*)src;
        I2S[r * PITCH2 + c] = (lf4){ab.x, ab.y, src[2], 0.f};
    }
    __syncthreads();

    const int row = tid >> 7, col = tid & 127;
    const int y = y0 + row, x = x0 + col;
    const int pix = y * WW + x;
    const double X = (double)x, Y = (double)y;
    const double xg = fma(M00, X, fma(M01, Y, M02));
    const double yg = fma(M10, X, fma(M11, Y, M12));
    const double fx = floor(xg), fy = floor(yg);
    const int xi = (int)fx, yi = (int)fy;
    const float tx = (float)(xg - fx), ty = (float)(yg - fy);
    const int sxi = xi - sx0, syi = yi - r0;
    const bool inwin = (sxi >= 1) && (sxi <= WS2c - 3) && (syi >= 1) && (syi <= 3);

    float Iw[3];
    if (inwin) bicubic3_lds(I2S, sxi, syi, tx, ty, Iw);
    else       bicubic3_gen(I2b, xg, yg, Iw);

    Iwb[pix * 3 + 0] = Iw[0];
    Iwb[pix * 3 + 1] = Iw[1];
    Iwb[pix * 3 + 2] = Iw[2];

    const bool v1 = (x >= DEL) && (x < WW - DEL) && (y >= DEL) && (y < HH - DEL);
    const double gx = rint(xg), gy = rint(yg);
    const bool wm = (gx >= (double)DEL && gx <= (double)(WW - DEL) &&
                     gy >= (double)DEL && gy <= (double)(HH - DEL));
    const bool m = v1 && wm;

    double rho_s = 0.0, cnt_s = 0.0;
    const float* c = I1b + pix * 3;
    if (m) {
#pragma unroll
        for (int ch = 0; ch < 3; ch++) {
            const float d = Iw[ch] - c[ch];
            DIb[pix * 3 + ch] = d;
            const float u = d * 20.0f;
            const float rho = 0.005f * (sqrtf(fmaf(u, u, 1.0f)) - 1.0f);
            rho_s += (double)rho;
        }
        cnt_s = 3.0;
    } else {
        DIb[pix * 3 + 0] = 0.0f;
        DIb[pix * 3 + 1] = 0.0f;
        DIb[pix * 3 + 2] = 0.0f;
    }
#pragma unroll
    for (int off = 32; off >= 1; off >>= 1) {
        rho_s += __shfl_down(rho_s, off, 64);
        cnt_s += __shfl_down(cnt_s, off, 64);
    }
    const int wid = tid >> 6, lane = tid & 63;
    if (lane == 0) { wsum[wid][0] = rho_s; wsum[wid][1] = cnt_s; }
    __syncthreads();
    if (tid < 2) {
        double sv = wsum[0][tid] + wsum[1][tid] + wsum[2][tid] +
                    wsum[3][tid] + wsum[4][tid] + wsum[5][tid];
        unsafeAtomicAdd(&Sf[b * 2 + tid], sv);
    }
}

extern "C" __global__ void k_finish(const double* __restrict__ p_fin,
                                    const double* __restrict__ Sf,
                                    float* __restrict__ out) {
    const int tid = threadIdx.x;  // 64 threads
    if (tid < BB * NPAR) out[tid] = (float)p_fin[tid];           // pf
    if (tid >= 48 && tid < 48 + BB) {
        const int b = tid - 48;
        out[48 + b] = (float)(Sf[b * 2 + 0] / fmax(Sf[b * 2 + 1], 1.0));  // err
    }
}

extern "C" void kernel_launch(void* const* d_in, const int* in_sizes, int n_in,
                              void* d_out, int out_size, void* d_ws, size_t ws_size,
                              hipStream_t stream) {
    const float* I1 = (const float*)d_in[0];
    const float* I2 = (const float*)d_in[1];
    const float* p0 = (const float*)d_in[2];
    float* out = (float*)d_out;

    // ws layout (8B-aligned):
    // [0)      p_store (MAXIT+1)*48 doubles = 4992 B
    // [4992)   done    (MAXIT+1)*8 ints     = 416 B
    // [5408)   S_all   MAXIT*8*24 doubles   = 18432 B
    // [23840)  Sf      16 doubles           = 128 B
    double* p_store = (double*)d_ws;
    int* done_flags = (int*)((char*)d_ws + 4992);
    double* S_all = (double*)((char*)d_ws + 5408);
    double* Sf = (double*)((char*)d_ws + 23840);

    k_init<<<1, 256, 0, stream>>>(p0, p_store, done_flags, S_all, Sf);
    dim3 gridI(NRT6 * 3, BB), blkI(384);
    for (int it = 0; it < MAXIT; it++) {
        k_iter<<<gridI, blkI, 0, stream>>>(I1, I2,
                                           p_store + (size_t)it * BB * NPAR,
                                           done_flags + it * BB,
                                           S_all + (size_t)it * BB * NACC);
        k_solve<<<1, 256, 0, stream>>>(S_all + (size_t)it * BB * NACC,
                                       p_store + (size_t)it * BB * NPAR,
                                       done_flags + it * BB,
                                       p_store + (size_t)(it + 1) * BB * NPAR,
                                       done_flags + (it + 1) * BB);
    }
    float* DI_out = out + 56;
    float* Iw_out = out + 56 + (size_t)BB * HWPIX * 3;
    dim3 gridF(128 * 3, BB), blkF(384);
    k_final_map<<<gridF, blkF, 0, stream>>>(I1, I2, p_store + (size_t)MAXIT * BB * NPAR,
                                            DI_out, Iw_out, Sf);
    k_finish<<<1, 64, 0, stream>>>(p_store + (size_t)MAXIT * BB * NPAR, Sf, out);
}

// Round 7
// 656.981 us; speedup vs baseline: 2.9452x; 1.0574x over previous
//
#include <hip/hip_runtime.h>
#include <math.h>

#define BB 8
#define HH 384
#define WW 384
#define NPAR 6
#define DEL 10
#define MAXIT 12
#define NACC 24
#define HWPIX (HH*WW)
#define NRT4 91                 // 4-row tiles covering rows 10..373 exactly
#define PITCH2 141              // staged I2 cols (max 140 used)
#define NR2 8                   // staged I2 rows

typedef float vf4 __attribute__((ext_vector_type(4)));
typedef vf4 uvf4 __attribute__((aligned(4)));      // 4B-aligned global dwordx4
typedef float f2v __attribute__((ext_vector_type(2), aligned(4)));
typedef float lf4 __attribute__((ext_vector_type(4)));  // 16B-aligned (LDS)

__device__ __forceinline__ vf4 ldv4(const float* p) { return *(const uvf4*)p; }

__device__ __forceinline__ float cubicw(float s) {
    s = fabsf(s);
    float s2 = s * s, s3 = s2 * s;
    float w1 = 1.5f * s3 - 2.5f * s2 + 1.0f;
    float w2 = -0.5f * s3 + 2.5f * s2 - 4.0f * s + 2.0f;
    return (s <= 1.0f) ? w1 : ((s < 2.0f) ? w2 : 0.0f);
}

// global fast-path bicubic (taps guaranteed in-bounds; drift fallback in k_iter)
__device__ __forceinline__ void bicubic3_fast(const float* __restrict__ Ib, double xg, double yg, float Iw[3]) {
    double fx = floor(xg), fy = floor(yg);
    float tx = (float)(xg - fx), ty = (float)(yg - fy);
    int xi = (int)fx, yi = (int)fy;
    float wx[4], wyv[4];
#pragma unroll
    for (int k = 0; k < 4; k++) { wx[k] = cubicw(tx - (float)(k - 1)); wyv[k] = cubicw(ty - (float)(k - 1)); }
    Iw[0] = 0.f; Iw[1] = 0.f; Iw[2] = 0.f;
    const float* base = Ib + (yi - 1) * (WW * 3) + (xi - 1) * 3;
#pragma unroll
    for (int j = 0; j < 4; j++) {
        const float* r = base + j * (WW * 3);
        vf4 v0 = ldv4(r), v1 = ldv4(r + 4), v2 = ldv4(r + 8);
        float r0 = fmaf(wx[0], v0.x, 0.f); r0 = fmaf(wx[1], v0.w, r0); r0 = fmaf(wx[2], v1.z, r0); r0 = fmaf(wx[3], v2.y, r0);
        float r1 = fmaf(wx[0], v0.y, 0.f); r1 = fmaf(wx[1], v1.x, r1); r1 = fmaf(wx[2], v1.w, r1); r1 = fmaf(wx[3], v2.z, r1);
        float r2 = fmaf(wx[0], v0.z, 0.f); r2 = fmaf(wx[1], v1.y, r2); r2 = fmaf(wx[2], v2.x, r2); r2 = fmaf(wx[3], v2.w, r2);
        Iw[0] = fmaf(wyv[j], r0, Iw[0]);
        Iw[1] = fmaf(wyv[j], r1, Iw[1]);
        Iw[2] = fmaf(wyv[j], r2, Iw[2]);
    }
}

// general bicubic with clip-to-edge (k_final_map fallback)
__device__ __forceinline__ void bicubic3_gen(const float* __restrict__ Ib, double xg, double yg, float Iw[3]) {
    double fx = floor(xg), fy = floor(yg);
    int xi = (int)fx, yi = (int)fy;
    float tx = (float)(xg - fx), ty = (float)(yg - fy);
    float wx[4], wyv[4];
    int xx[4], yy[4];
#pragma unroll
    for (int k = 0; k < 4; k++) {
        wx[k] = cubicw(tx - (float)(k - 1)); wyv[k] = cubicw(ty - (float)(k - 1));
        xx[k] = min(max(xi + k - 1, 0), WW - 1);
        yy[k] = min(max(yi + k - 1, 0), HH - 1);
    }
    Iw[0] = 0.f; Iw[1] = 0.f; Iw[2] = 0.f;
#pragma unroll
    for (int j = 0; j < 4; j++) {
        const float* row = Ib + yy[j] * (WW * 3);
        float r0 = 0.f, r1 = 0.f, r2 = 0.f;
#pragma unroll
        for (int k = 0; k < 4; k++) {
            const float* q = row + xx[k] * 3;
            r0 = fmaf(wx[k], q[0], r0); r1 = fmaf(wx[k], q[1], r1); r2 = fmaf(wx[k], q[2], r2);
        }
        Iw[0] = fmaf(wyv[j], r0, Iw[0]);
        Iw[1] = fmaf(wyv[j], r1, Iw[1]);
        Iw[2] = fmaf(wyv[j], r2, Iw[2]);
    }
}

// LDS bicubic from float4-padded staged tile (identical fma order)
__device__ __forceinline__ void bicubic3_lds(const lf4* __restrict__ T, int ssx, int ssy,
                                             float tx, float ty, float Iw[3]) {
    float wx[4], wyv[4];
#pragma unroll
    for (int k = 0; k < 4; k++) { wx[k] = cubicw(tx - (float)(k - 1)); wyv[k] = cubicw(ty - (float)(k - 1)); }
    Iw[0] = 0.f; Iw[1] = 0.f; Iw[2] = 0.f;
    const lf4* bp = T + (ssy - 1) * PITCH2 + (ssx - 1);
#pragma unroll
    for (int j = 0; j < 4; j++) {
        lf4 t0 = bp[j * PITCH2 + 0], t1 = bp[j * PITCH2 + 1], t2 = bp[j * PITCH2 + 2], t3 = bp[j * PITCH2 + 3];
        float r0 = fmaf(wx[0], t0.x, 0.f); r0 = fmaf(wx[1], t1.x, r0); r0 = fmaf(wx[2], t2.x, r0); r0 = fmaf(wx[3], t3.x, r0);
        float r1 = fmaf(wx[0], t0.y, 0.f); r1 = fmaf(wx[1], t1.y, r1); r1 = fmaf(wx[2], t2.y, r1); r1 = fmaf(wx[3], t3.y, r1);
        float r2 = fmaf(wx[0], t0.z, 0.f); r2 = fmaf(wx[1], t1.z, r2); r2 = fmaf(wx[2], t2.z, r2); r2 = fmaf(wx[3], t3.z, r2);
        Iw[0] = fmaf(wyv[j], r0, Iw[0]);
        Iw[1] = fmaf(wyv[j], r1, Iw[1]);
        Iw[2] = fmaf(wyv[j], r2, Iw[2]);
    }
}

extern "C" __global__ __launch_bounds__(256)
void k_init(const float* __restrict__ p0, double* __restrict__ p_store,
            int* __restrict__ done0, double* __restrict__ S_all,
            double* __restrict__ Sf) {
    int tid = threadIdx.x;
    for (int i = tid; i < MAXIT * BB * NACC; i += 256) S_all[i] = 0.0;
    if (tid < 2 * BB) Sf[tid] = 0.0;
    if (tid < BB * NPAR) p_store[tid] = (double)p0[tid];
    if (tid < BB) done0[tid] = 0;
}

// 4-row x 128-col tile; wave w owns row y0+w (2 px/lane). I2 LDS-staged.
// Reduction: 1 shuffle step + LDS scratch (aliased over I2 stage) + 24-thread fold.
extern "C" __global__ __launch_bounds__(256, 8)
void k_iter(const float* __restrict__ I1, const float* __restrict__ I2,
            const double* __restrict__ p_in, const int* __restrict__ done_in,
            double* __restrict__ S) {
    __shared__ lf4 SMEM[NR2 * PITCH2];      // 18048 B; reused as reduction scratch
    const int b = blockIdx.y;
    if (done_in[b]) return;                 // frozen batch: S stays zero
    const int tid = threadIdx.x;
    const int tix = blockIdx.x;             // 0..272
    const int rt = tix / 3, win = tix - rt * 3;
    const int y0 = 10 + rt * 4;             // rows y0..y0+3, all in [10,373]
    const int x0 = 10 + win * 128;
    const int W = (win == 2) ? 108 : 128;
    const int WS2c = W + 12;
    const int sx0 = x0 - 6;

    const double* p = p_in + b * NPAR;
    const double M00 = 1.0 + p[2], M01 = p[3], M02 = p[0];
    const double M10 = p[4], M11 = 1.0 + p[5], M12 = p[1];
    const float* I1b = I1 + (size_t)b * HWPIX * 3;
    const float* I2b = I2 + (size_t)b * HWPIX * 3;

    const double ygc = M10 * (double)(x0 + 64) + M11 * ((double)y0 + 1.5) + M12;
    const int r0 = (int)fmin(fmax(floor(ygc) - 3.0, -100000.0), 100000.0);

    // stage I2 rows r0..r0+7 (row+col clamped: memory-safe, matches clip-to-edge)
    for (int i = tid; i < NR2 * WS2c; i += 256) {
        const int r = i / WS2c, c = i - r * WS2c;
        const int gr = min(max(r0 + r, 0), HH - 1);
        const int gc = min(sx0 + c, WW - 1);           // sx0 >= 4, no low clamp needed
        const float* src = I2b + (gr * WW + gc) * 3;
        f2v ab = *(const f2v*)src;
        SMEM[r * PITCH2 + c] = (lf4){ab.x, ab.y, src[2], 0.f};
    }
    __syncthreads();

    const int wid = tid >> 6, lane = tid & 63;
    const int y = y0 + wid;                 // wave-uniform row, <= 373
    const double Y = (double)y;
    const double Bx = M01 * Y + M02;
    const double By = M11 * Y + M12;

    double s[13];
#pragma unroll
    for (int i = 0; i < 13; i++) s[i] = 0.0;
    // s: 0=T0 1=T0X 2=T1 3=T1X 4=A 5=AX 6=AXX 7=B 8=BX 9=BXX 10=C 11=CX 12=CXX

#pragma unroll
    for (int step = 0; step < 2; step++) {
        const int col = lane + 64 * step;
        const int x = x0 + col;
        const double X = (double)x;
        const double xg = fma(M00, X, Bx);
        const double yg = fma(M10, X, By);
        const double gx = rint(xg), gy = rint(yg);   // half-to-even like jnp.round
        const bool ok = (col < W) &&
                        (gx >= (double)DEL && gx <= (double)(WW - DEL) &&
                         gy >= (double)DEL && gy <= (double)(HH - DEL));
        const double fx = floor(xg), fy = floor(yg);
        const int xi = (int)fx, yi = (int)fy;
        const float tx = (float)(xg - fx), ty = (float)(yg - fy);
        const int sxi = xi - sx0, syi = yi - r0;
        const bool inwin = ok && (sxi >= 1) && (sxi <= WS2c - 3) && (syi >= 1) && (syi <= NR2 - 3);

        float Iw[3];
        if (ok && !inwin) {
            bicubic3_fast(I2b, xg, yg, Iw);   // rare drift fallback
        } else {
            const int ssx = inwin ? sxi : 8;
            const int ssy = inwin ? syi : 2;
            bicubic3_lds(SMEM, ssx, ssy, tx, ty, Iw);
        }

        // I1 neighborhood via coalesced global vector loads (interior-clamped)
        const int xc = min(x, WW - DEL - 1);
        const int pixL = y * WW + xc;
        const float* c = I1b + pixL * 3;
        vf4 u0 = ldv4(c - 3);          // cl0 cl1 cl2 c0
        vf4 u1 = ldv4(c + 1);          // c1 c2 cr0 cr1
        float cr2 = c[5];
        vf4 uu = ldv4(c - WW * 3);     // cu0 cu1 cu2 .
        vf4 ud = ldv4(c + WW * 3);     // cd0 cd1 cd2 .

        const float cl[3] = {u0.x, u0.y, u0.z};
        const float cv[3] = {u0.w, u1.x, u1.y};
        const float cr[3] = {u1.z, u1.w, cr2};
        const float cu[3] = {uu.x, uu.y, uu.z};
        const float cd[3] = {ud.x, ud.y, ud.z};

        const float msk = ok ? 1.0f : 0.0f;
        float Af = 0.f, Bf = 0.f, Cf = 0.f, T0f = 0.f, T1f = 0.f;
#pragma unroll
        for (int ch = 0; ch < 3; ch++) {
            const float Ix = (cr[ch] - cl[ch]) * 0.5f;
            const float Iy = (cd[ch] - cu[ch]) * 0.5f;
            const float d = Iw[ch] - cv[ch];
            const float u = d * 20.0f;
            const float w = msk / sqrtf(fmaf(u, u, 1.0f));
            const float wd = w * d;
            T0f = fmaf(Ix, wd, T0f);
            T1f = fmaf(Iy, wd, T1f);
            const float wIx = w * Ix;
            Af = fmaf(wIx, Ix, Af);
            Bf = fmaf(wIx, Iy, Bf);
            Cf = fmaf(w * Iy, Iy, Cf);
        }
        const double T0 = (double)T0f, T1 = (double)T1f;
        const double A = (double)Af, Bd = (double)Bf, Cd = (double)Cf;
        const double XX = X * X;
        s[0] += T0;  s[1] = fma(T0, X, s[1]);
        s[2] += T1;  s[3] = fma(T1, X, s[3]);
        s[4] += A;   s[5] = fma(A, X, s[5]);   s[6] = fma(A, XX, s[6]);
        s[7] += Bd;  s[8] = fma(Bd, X, s[8]);  s[9] = fma(Bd, XX, s[9]);
        s[10] += Cd; s[11] = fma(Cd, X, s[11]); s[12] = fma(Cd, XX, s[12]);
    }

    // one shuffle fold (lane+32), then lanes 0..31 dump raw partials to LDS
#pragma unroll
    for (int i = 0; i < 13; i++) s[i] += __shfl_down(s[i], 32, 64);

    __syncthreads();                         // all I2S reads complete; alias as scratch
    double* scr = (double*)SMEM;             // 4 waves x 32 lanes x 13 f64 = 13312 B
    if (lane < 32) {
        double* o = scr + ((size_t)(wid * 32 + lane)) * 13;
#pragma unroll
        for (int i = 0; i < 13; i++) o[i] = s[i];
    }
    __syncthreads();

    if (tid < NACC) {
        // component -> (s index, Y power)
        const int comp[NACC] = {0,1,0, 2,3,2, 4,5,4, 6,5,4, 7,8,7, 9,8,7, 10,11,10, 12,11,10};
        const int ypw[NACC]  = {0,0,1, 0,0,1, 0,0,1, 0,1,2, 0,0,1, 0,1,2, 0,0,1,   0,1,2};
        const int cix = comp[tid], pw = ypw[tid];
        double acc = 0.0;
        for (int w = 0; w < 4; w++) {
            const double* basep = scr + ((size_t)(w * 32)) * 13 + cix;
            double part = 0.0;
            for (int l = 0; l < 32; l++) part += basep[(size_t)l * 13];
            const double Yw = (double)(y0 + w);
            const double f = (pw == 0) ? 1.0 : ((pw == 1) ? Yw : Yw * Yw);
            acc = fma(f, part, acc);
        }
        unsafeAtomicAdd(&S[b * NACC + tid], acc);
    }
}

extern "C" __global__ __launch_bounds__(256)
void k_solve(const double* __restrict__ S_it, const double* __restrict__ p_in,
             const int* __restrict__ done_in, double* __restrict__ p_out,
             int* __restrict__ done_out) {
    __shared__ double S[BB][NACC];
    const int tid = threadIdx.x;
    if (tid < BB * NACC) S[tid / NACC][tid % NACC] = S_it[tid];
    __syncthreads();
    if (tid >= BB) return;
    const int b = tid;
    if (done_in[b]) {
        done_out[b] = 1;
        for (int i = 0; i < NPAR; i++) p_out[b * NPAR + i] = p_in[b * NPAR + i];
        return;
    }
    const double* Sb = S[b];
    double bv[6] = {Sb[0], Sb[3], Sb[1], Sb[2], Sb[4], Sb[5]};
    double Hm[6][6];
    Hm[0][0] = Sb[6];  Hm[0][1] = Sb[12]; Hm[0][2] = Sb[7];  Hm[0][3] = Sb[8];  Hm[0][4] = Sb[13]; Hm[0][5] = Sb[14];
    Hm[1][1] = Sb[18]; Hm[1][2] = Sb[13]; Hm[1][3] = Sb[14]; Hm[1][4] = Sb[19]; Hm[1][5] = Sb[20];
    Hm[2][2] = Sb[9];  Hm[2][3] = Sb[10]; Hm[2][4] = Sb[15]; Hm[2][5] = Sb[16];
    Hm[3][3] = Sb[11]; Hm[3][4] = Sb[16]; Hm[3][5] = Sb[17];
    Hm[4][4] = Sb[21]; Hm[4][5] = Sb[22];
    Hm[5][5] = Sb[23];
    for (int i = 0; i < 6; i++)
        for (int jj = 0; jj < i; jj++) Hm[i][jj] = Hm[jj][i];
    for (int i = 0; i < 6; i++) Hm[i][i] += 1e-6;

    double Aa[6][7];
    for (int i = 0; i < 6; i++) {
        for (int jj = 0; jj < 6; jj++) Aa[i][jj] = Hm[i][jj];
        Aa[i][6] = bv[i];
    }
    for (int k = 0; k < 6; k++) {
        int piv = k;
        double mx = fabs(Aa[k][k]);
        for (int r = k + 1; r < 6; r++) {
            double v = fabs(Aa[r][k]);
            if (v > mx) { mx = v; piv = r; }
        }
        if (piv != k)
            for (int jj = k; jj < 7; jj++) { double t = Aa[k][jj]; Aa[k][jj] = Aa[piv][jj]; Aa[piv][jj] = t; }
        const double inv = 1.0 / Aa[k][k];
        for (int r = k + 1; r < 6; r++) {
            const double f = Aa[r][k] * inv;
            for (int jj = k; jj < 7; jj++) Aa[r][jj] -= f * Aa[k][jj];
        }
    }
    double dp[6];
    for (int i = 5; i >= 0; i--) {
        double sv = Aa[i][6];
        for (int jj = i + 1; jj < 6; jj++) sv -= Aa[i][jj] * dp[jj];
        dp[i] = sv / Aa[i][i];
    }
    const double nrm = sqrt(dp[0]*dp[0] + dp[1]*dp[1] + dp[2]*dp[2] + dp[3]*dp[3] + dp[4]*dp[4] + dp[5]*dp[5]);
    const int conv = (nrm < 1e-3) ? 1 : 0;

    const double* pc = p_in + b * NPAR;
    const double m00 = 1.0 + pc[2], m01 = pc[3], m02 = pc[0];
    const double m10 = pc[4], m11 = 1.0 + pc[5], m12 = pc[1];
    const double q00 = 1.0 + dp[2], q01 = dp[3], q02 = dp[0];
    const double q10 = dp[4], q11 = 1.0 + dp[5], q12 = dp[1];
    const double det = q00 * q11 - q01 * q10;
    const double i00 = q11 / det, i01 = -q01 / det;
    const double i10 = -q10 / det, i11 = q00 / det;
    const double it0 = -(i00 * q02 + i01 * q12);
    const double it1 = -(i10 * q02 + i11 * q12);
    const double n00 = m00 * i00 + m01 * i10;
    const double n01 = m00 * i01 + m01 * i11;
    const double n02 = m00 * it0 + m01 * it1 + m02;
    const double n10 = m10 * i00 + m11 * i10;
    const double n11 = m10 * i01 + m11 * i11;
    const double n12 = m10 * it0 + m11 * it1 + m12;
    p_out[b * NPAR + 0] = n02;
    p_out[b * NPAR + 1] = n12;
    p_out[b * NPAR + 2] = n00 - 1.0;
    p_out[b * NPAR + 3] = n01;
    p_out[b * NPAR + 4] = n10;
    p_out[b * NPAR + 5] = n11 - 1.0;
    done_out[b] = conv;
}

// 4-row x 128-col tiles over the FULL image (incl. borders). 2 px/thread.
extern "C" __global__ __launch_bounds__(256)
void k_final_map(const float* __restrict__ I1, const float* __restrict__ I2,
                 const double* __restrict__ p_fin, float* __restrict__ DI_out,
                 float* __restrict__ Iw_out, double* __restrict__ Sf) {
    __shared__ lf4 I2S[NR2 * PITCH2];
    __shared__ double wsum[4][2];
    const int tid = threadIdx.x;
    const int b = blockIdx.y;
    const int tix = blockIdx.x;                 // 0..287
    const int rt = tix / 3, win = tix - rt * 3;
    const int y0 = rt * 4;
    const int x0 = win * 128;
    const int WS2c = 140;
    const int sx0 = x0 - 6;

    const double* p = p_fin + b * NPAR;
    const double M00 = 1.0 + p[2], M01 = p[3], M02 = p[0];
    const double M10 = p[4], M11 = 1.0 + p[5], M12 = p[1];
    const float* I1b = I1 + (size_t)b * HWPIX * 3;
    const float* I2b = I2 + (size_t)b * HWPIX * 3;
    float* DIb = DI_out + (size_t)b * HWPIX * 3;
    float* Iwb = Iw_out + (size_t)b * HWPIX * 3;

    const double ygc = M10 * (double)(x0 + 64) + M11 * ((double)y0 + 1.5) + M12;
    const int r0 = (int)fmin(fmax(floor(ygc) - 3.0, -100000.0), 100000.0);

    for (int i = tid; i < NR2 * WS2c; i += 256) {
        const int r = i / WS2c, c = i - r * WS2c;
        const int gr = min(max(r0 + r, 0), HH - 1);    // clamped staging == clip-to-edge
        const int gc = min(max(sx0 + c, 0), WW - 1);
        const float* src = I2b + (gr * WW + gc) * 3;
        f2v ab = *(const f2v*)src;
        I2S[r * PITCH2 + c] = (lf4){ab.x, ab.y, src[2], 0.f};
    }
    __syncthreads();

    double rho_s = 0.0, cnt_s = 0.0;
#pragma unroll
    for (int step = 0; step < 2; step++) {
        const int idx = step * 256 + tid;        // 0..511
        const int row = idx >> 7, col = idx & 127;
        const int y = y0 + row, x = x0 + col;
        const int pix = y * WW + x;
        const double X = (double)x, Y = (double)y;
        const double xg = fma(M00, X, fma(M01, Y, M02));
        const double yg = fma(M10, X, fma(M11, Y, M12));
        const double fx = floor(xg), fy = floor(yg);
        const int xi = (int)fx, yi = (int)fy;
        const float tx = (float)(xg - fx), ty = (float)(yg - fy);
        const int sxi = xi - sx0, syi = yi - r0;
        const bool inwin = (sxi >= 1) && (sxi <= WS2c - 3) && (syi >= 1) && (syi <= NR2 - 3);

        float Iw[3];
        if (inwin) bicubic3_lds(I2S, sxi, syi, tx, ty, Iw);
        else       bicubic3_gen(I2b, xg, yg, Iw);

        Iwb[pix * 3 + 0] = Iw[0];
        Iwb[pix * 3 + 1] = Iw[1];
        Iwb[pix * 3 + 2] = Iw[2];

        const bool v1 = (x >= DEL) && (x < WW - DEL) && (y >= DEL) && (y < HH - DEL);
        const double gx = rint(xg), gy = rint(yg);
        const bool wm = (gx >= (double)DEL && gx <= (double)(WW - DEL) &&
                         gy >= (double)DEL && gy <= (double)(HH - DEL));
        const bool m = v1 && wm;
        const float* c = I1b + pix * 3;
        if (m) {
#pragma unroll
            for (int ch = 0; ch < 3; ch++) {
                const float d = Iw[ch] - c[ch];
                DIb[pix * 3 + ch] = d;
                const float u = d * 20.0f;
                const float rho = 0.005f * (sqrtf(fmaf(u, u, 1.0f)) - 1.0f);
                rho_s += (double)rho;
            }
            cnt_s += 3.0;
        } else {
            DIb[pix * 3 + 0] = 0.0f;
            DIb[pix * 3 + 1] = 0.0f;
            DIb[pix * 3 + 2] = 0.0f;
        }
    }
#pragma unroll
    for (int off = 32; off >= 1; off >>= 1) {
        rho_s += __shfl_down(rho_s, off, 64);
        cnt_s += __shfl_down(cnt_s, off, 64);
    }
    const int wid = tid >> 6, lane = tid & 63;
    if (lane == 0) { wsum[wid][0] = rho_s; wsum[wid][1] = cnt_s; }
    __syncthreads();
    if (tid < 2) {
        double sv = wsum[0][tid] + wsum[1][tid] + wsum[2][tid] + wsum[3][tid];
        unsafeAtomicAdd(&Sf[b * 2 + tid], sv);
    }
}

extern "C" __global__ void k_finish(const double* __restrict__ p_fin,
                                    const double* __restrict__ Sf,
                                    float* __restrict__ out) {
    const int tid = threadIdx.x;  // 64 threads
    if (tid < BB * NPAR) out[tid] = (float)p_fin[tid];           // pf
    if (tid >= 48 && tid < 48 + BB) {
        const int b = tid - 48;
        out[48 + b] = (float)(Sf[b * 2 + 0] / fmax(Sf[b * 2 + 1], 1.0));  // err
    }
}

extern "C" void kernel_launch(void* const* d_in, const int* in_sizes, int n_in,
                              void* d_out, int out_size, void* d_ws, size_t ws_size,
                              hipStream_t stream) {
    const float* I1 = (const float*)d_in[0];
    const float* I2 = (const float*)d_in[1];
    const float* p0 = (const float*)d_in[2];
    float* out = (float*)d_out;

    // ws layout (8B-aligned):
    // [0)      p_store (MAXIT+1)*48 doubles = 4992 B
    // [4992)   done    (MAXIT+1)*8 ints     = 416 B
    // [5408)   S_all   MAXIT*8*24 doubles   = 18432 B
    // [23840)  Sf      16 doubles           = 128 B
    double* p_store = (double*)d_ws;
    int* done_flags = (int*)((char*)d_ws + 4992);
    double* S_all = (double*)((char*)d_ws + 5408);
    double* Sf = (double*)((char*)d_ws + 23840);

    k_init<<<1, 256, 0, stream>>>(p0, p_store, done_flags, S_all, Sf);
    dim3 gridI(NRT4 * 3, BB), blkI(256);
    for (int it = 0; it < MAXIT; it++) {
        k_iter<<<gridI, blkI, 0, stream>>>(I1, I2,
                                           p_store + (size_t)it * BB * NPAR,
                                           done_flags + it * BB,
                                           S_all + (size_t)it * BB * NACC);
        k_solve<<<1, 256, 0, stream>>>(S_all + (size_t)it * BB * NACC,
                                       p_store + (size_t)it * BB * NPAR,
                                       done_flags + it * BB,
                                       p_store + (size_t)(it + 1) * BB * NPAR,
                                       done_flags + (it + 1) * BB);
    }
    float* DI_out = out + 56;
    float* Iw_out = out + 56 + (size_t)BB * HWPIX * 3;
    dim3 gridF(96 * 3, BB), blkF(256);
    k_final_map<<<gridF, blkF, 0, stream>>>(I1, I2, p_store + (size_t)MAXIT * BB * NPAR,
                                            DI_out, Iw_out, Sf);
    k_finish<<<1, 64, 0, stream>>>(p_store + (size_t)MAXIT * BB * NPAR, Sf, out);
}

// Round 8
// 551.394 us; speedup vs baseline: 3.5091x; 1.1915x over previous
//
#include <hip/hip_runtime.h>
#include <math.h>

#define BB 8
#define HH 384
#define WW 384
#define NPAR 6
#define DEL 10
#define MAXIT 12
#define NACC 24
#define HWPIX (HH*WW)
#define NRT4 91                 // 4-row tiles covering rows 10..373 exactly
#define PITCH2 141              // staged I2 cols (max 140 used)
#define NR2 8                   // staged I2 rows

typedef float vf4 __attribute__((ext_vector_type(4)));
typedef vf4 uvf4 __attribute__((aligned(4)));      // 4B-aligned global dwordx4
typedef float f2v __attribute__((ext_vector_type(2), aligned(4)));
typedef float lf4 __attribute__((ext_vector_type(4)));  // 16B-aligned (LDS)

__device__ __forceinline__ vf4 ldv4(const float* p) { return *(const uvf4*)p; }

__device__ __forceinline__ float cubicw(float s) {
    s = fabsf(s);
    float s2 = s * s, s3 = s2 * s;
    float w1 = 1.5f * s3 - 2.5f * s2 + 1.0f;
    float w2 = -0.5f * s3 + 2.5f * s2 - 4.0f * s + 2.0f;
    return (s <= 1.0f) ? w1 : ((s < 2.0f) ? w2 : 0.0f);
}

// global fast-path bicubic (taps guaranteed in-bounds; drift fallback in k_iter)
__device__ __forceinline__ void bicubic3_fast(const float* __restrict__ Ib, double xg, double yg, float Iw[3]) {
    double fx = floor(xg), fy = floor(yg);
    float tx = (float)(xg - fx), ty = (float)(yg - fy);
    int xi = (int)fx, yi = (int)fy;
    float wx[4], wyv[4];
#pragma unroll
    for (int k = 0; k < 4; k++) { wx[k] = cubicw(tx - (float)(k - 1)); wyv[k] = cubicw(ty - (float)(k - 1)); }
    Iw[0] = 0.f; Iw[1] = 0.f; Iw[2] = 0.f;
    const float* base = Ib + (yi - 1) * (WW * 3) + (xi - 1) * 3;
#pragma unroll
    for (int j = 0; j < 4; j++) {
        const float* r = base + j * (WW * 3);
        vf4 v0 = ldv4(r), v1 = ldv4(r + 4), v2 = ldv4(r + 8);
        float r0 = fmaf(wx[0], v0.x, 0.f); r0 = fmaf(wx[1], v0.w, r0); r0 = fmaf(wx[2], v1.z, r0); r0 = fmaf(wx[3], v2.y, r0);
        float r1 = fmaf(wx[0], v0.y, 0.f); r1 = fmaf(wx[1], v1.x, r1); r1 = fmaf(wx[2], v1.w, r1); r1 = fmaf(wx[3], v2.z, r1);
        float r2 = fmaf(wx[0], v0.z, 0.f); r2 = fmaf(wx[1], v1.y, r2); r2 = fmaf(wx[2], v2.x, r2); r2 = fmaf(wx[3], v2.w, r2);
        Iw[0] = fmaf(wyv[j], r0, Iw[0]);
        Iw[1] = fmaf(wyv[j], r1, Iw[1]);
        Iw[2] = fmaf(wyv[j], r2, Iw[2]);
    }
}

// general bicubic with clip-to-edge (k_final_map fallback)
__device__ __forceinline__ void bicubic3_gen(const float* __restrict__ Ib, double xg, double yg, float Iw[3]) {
    double fx = floor(xg), fy = floor(yg);
    int xi = (int)fx, yi = (int)fy;
    float tx = (float)(xg - fx), ty = (float)(yg - fy);
    float wx[4], wyv[4];
    int xx[4], yy[4];
#pragma unroll
    for (int k = 0; k < 4; k++) {
        wx[k] = cubicw(tx - (float)(k - 1)); wyv[k] = cubicw(ty - (float)(k - 1));
        xx[k] = min(max(xi + k - 1, 0), WW - 1);
        yy[k] = min(max(yi + k - 1, 0), HH - 1);
    }
    Iw[0] = 0.f; Iw[1] = 0.f; Iw[2] = 0.f;
#pragma unroll
    for (int j = 0; j < 4; j++) {
        const float* row = Ib + yy[j] * (WW * 3);
        float r0 = 0.f, r1 = 0.f, r2 = 0.f;
#pragma unroll
        for (int k = 0; k < 4; k++) {
            const float* q = row + xx[k] * 3;
            r0 = fmaf(wx[k], q[0], r0); r1 = fmaf(wx[k], q[1], r1); r2 = fmaf(wx[k], q[2], r2);
        }
        Iw[0] = fmaf(wyv[j], r0, Iw[0]);
        Iw[1] = fmaf(wyv[j], r1, Iw[1]);
        Iw[2] = fmaf(wyv[j], r2, Iw[2]);
    }
}

// LDS bicubic from float4-padded staged tile (identical fma order)
__device__ __forceinline__ void bicubic3_lds(const lf4* __restrict__ T, int ssx, int ssy,
                                             float tx, float ty, float Iw[3]) {
    float wx[4], wyv[4];
#pragma unroll
    for (int k = 0; k < 4; k++) { wx[k] = cubicw(tx - (float)(k - 1)); wyv[k] = cubicw(ty - (float)(k - 1)); }
    Iw[0] = 0.f; Iw[1] = 0.f; Iw[2] = 0.f;
    const lf4* bp = T + (ssy - 1) * PITCH2 + (ssx - 1);
#pragma unroll
    for (int j = 0; j < 4; j++) {
        lf4 t0 = bp[j * PITCH2 + 0], t1 = bp[j * PITCH2 + 1], t2 = bp[j * PITCH2 + 2], t3 = bp[j * PITCH2 + 3];
        float r0 = fmaf(wx[0], t0.x, 0.f); r0 = fmaf(wx[1], t1.x, r0); r0 = fmaf(wx[2], t2.x, r0); r0 = fmaf(wx[3], t3.x, r0);
        float r1 = fmaf(wx[0], t0.y, 0.f); r1 = fmaf(wx[1], t1.y, r1); r1 = fmaf(wx[2], t2.y, r1); r1 = fmaf(wx[3], t3.y, r1);
        float r2 = fmaf(wx[0], t0.z, 0.f); r2 = fmaf(wx[1], t1.z, r2); r2 = fmaf(wx[2], t2.z, r2); r2 = fmaf(wx[3], t3.z, r2);
        Iw[0] = fmaf(wyv[j], r0, Iw[0]);
        Iw[1] = fmaf(wyv[j], r1, Iw[1]);
        Iw[2] = fmaf(wyv[j], r2, Iw[2]);
    }
}

extern "C" __global__ __launch_bounds__(256)
void k_init(const float* __restrict__ p0, double* __restrict__ p_store,
            int* __restrict__ done0, double* __restrict__ S_all,
            double* __restrict__ Sf) {
    int tid = threadIdx.x;
    for (int i = tid; i < MAXIT * BB * NACC; i += 256) S_all[i] = 0.0;
    if (tid < 2 * BB) Sf[tid] = 0.0;
    if (tid < BB * NPAR) p_store[tid] = (double)p0[tid];
    if (tid < BB) done0[tid] = 0;
}

// 4-row x 128-col tile; wave w owns row y0+w (2 px/lane). I2 LDS-staged.
// NOTE: no min-waves in launch_bounds — R7's (256,8) capped VGPR at 32 and
// spilled 90 MB/iter to scratch (WRITE_SIZE 59 MB). Natural VGPR ~60 <= 64
// already allows 8 waves/SIMD.
extern "C" __global__ __launch_bounds__(256)
void k_iter(const float* __restrict__ I1, const float* __restrict__ I2,
            const double* __restrict__ p_in, const int* __restrict__ done_in,
            double* __restrict__ S) {
    __shared__ lf4 SMEM[NR2 * PITCH2];      // 18048 B; reused as reduction scratch
    const int b = blockIdx.y;
    if (done_in[b]) return;                 // frozen batch: S stays zero
    const int tid = threadIdx.x;
    const int tix = blockIdx.x;             // 0..272
    const int rt = tix / 3, win = tix - rt * 3;
    const int y0 = 10 + rt * 4;             // rows y0..y0+3, all in [10,373]
    const int x0 = 10 + win * 128;
    const int W = (win == 2) ? 108 : 128;
    const int WS2c = W + 12;
    const int sx0 = x0 - 6;

    const double* p = p_in + b * NPAR;
    const double M00 = 1.0 + p[2], M01 = p[3], M02 = p[0];
    const double M10 = p[4], M11 = 1.0 + p[5], M12 = p[1];
    const float* I1b = I1 + (size_t)b * HWPIX * 3;
    const float* I2b = I2 + (size_t)b * HWPIX * 3;

    const double ygc = M10 * (double)(x0 + 64) + M11 * ((double)y0 + 1.5) + M12;
    const int r0 = (int)fmin(fmax(floor(ygc) - 3.0, -100000.0), 100000.0);

    // stage I2 rows r0..r0+7 (row+col clamped: memory-safe, matches clip-to-edge)
    for (int i = tid; i < NR2 * WS2c; i += 256) {
        const int r = i / WS2c, c = i - r * WS2c;
        const int gr = min(max(r0 + r, 0), HH - 1);
        const int gc = min(sx0 + c, WW - 1);           // sx0 >= 4, no low clamp needed
        const float* src = I2b + (gr * WW + gc) * 3;
        f2v ab = *(const f2v*)src;
        SMEM[r * PITCH2 + c] = (lf4){ab.x, ab.y, src[2], 0.f};
    }
    __syncthreads();

    const int wid = tid >> 6, lane = tid & 63;
    const int y = y0 + wid;                 // wave-uniform row, <= 373
    const double Y = (double)y;
    const double Bx = M01 * Y + M02;
    const double By = M11 * Y + M12;

    double s[13];
#pragma unroll
    for (int i = 0; i < 13; i++) s[i] = 0.0;
    // s: 0=T0 1=T0X 2=T1 3=T1X 4=A 5=AX 6=AXX 7=B 8=BX 9=BXX 10=C 11=CX 12=CXX

#pragma unroll
    for (int step = 0; step < 2; step++) {
        const int col = lane + 64 * step;
        const int x = x0 + col;
        const double X = (double)x;
        const double xg = fma(M00, X, Bx);
        const double yg = fma(M10, X, By);
        const double gx = rint(xg), gy = rint(yg);   // half-to-even like jnp.round
        const bool ok = (col < W) &&
                        (gx >= (double)DEL && gx <= (double)(WW - DEL) &&
                         gy >= (double)DEL && gy <= (double)(HH - DEL));
        const double fx = floor(xg), fy = floor(yg);
        const int xi = (int)fx, yi = (int)fy;
        const float tx = (float)(xg - fx), ty = (float)(yg - fy);
        const int sxi = xi - sx0, syi = yi - r0;
        const bool inwin = ok && (sxi >= 1) && (sxi <= WS2c - 3) && (syi >= 1) && (syi <= NR2 - 3);

        float Iw[3];
        if (ok && !inwin) {
            bicubic3_fast(I2b, xg, yg, Iw);   // rare drift fallback
        } else {
            const int ssx = inwin ? sxi : 8;
            const int ssy = inwin ? syi : 2;
            bicubic3_lds(SMEM, ssx, ssy, tx, ty, Iw);
        }

        // I1 neighborhood via coalesced global vector loads (interior-clamped)
        const int xc = min(x, WW - DEL - 1);
        const int pixL = y * WW + xc;
        const float* c = I1b + pixL * 3;
        vf4 u0 = ldv4(c - 3);          // cl0 cl1 cl2 c0
        vf4 u1 = ldv4(c + 1);          // c1 c2 cr0 cr1
        float cr2 = c[5];
        vf4 uu = ldv4(c - WW * 3);     // cu0 cu1 cu2 .
        vf4 ud = ldv4(c + WW * 3);     // cd0 cd1 cd2 .

        const float cl[3] = {u0.x, u0.y, u0.z};
        const float cv[3] = {u0.w, u1.x, u1.y};
        const float cr[3] = {u1.z, u1.w, cr2};
        const float cu[3] = {uu.x, uu.y, uu.z};
        const float cd[3] = {ud.x, ud.y, ud.z};

        const float msk = ok ? 1.0f : 0.0f;
        float Af = 0.f, Bf = 0.f, Cf = 0.f, T0f = 0.f, T1f = 0.f;
#pragma unroll
        for (int ch = 0; ch < 3; ch++) {
            const float Ix = (cr[ch] - cl[ch]) * 0.5f;
            const float Iy = (cd[ch] - cu[ch]) * 0.5f;
            const float d = Iw[ch] - cv[ch];
            const float u = d * 20.0f;
            const float w = msk / sqrtf(fmaf(u, u, 1.0f));
            const float wd = w * d;
            T0f = fmaf(Ix, wd, T0f);
            T1f = fmaf(Iy, wd, T1f);
            const float wIx = w * Ix;
            Af = fmaf(wIx, Ix, Af);
            Bf = fmaf(wIx, Iy, Bf);
            Cf = fmaf(w * Iy, Iy, Cf);
        }
        const double T0 = (double)T0f, T1 = (double)T1f;
        const double A = (double)Af, Bd = (double)Bf, Cd = (double)Cf;
        const double XX = X * X;
        s[0] += T0;  s[1] = fma(T0, X, s[1]);
        s[2] += T1;  s[3] = fma(T1, X, s[3]);
        s[4] += A;   s[5] = fma(A, X, s[5]);   s[6] = fma(A, XX, s[6]);
        s[7] += Bd;  s[8] = fma(Bd, X, s[8]);  s[9] = fma(Bd, XX, s[9]);
        s[10] += Cd; s[11] = fma(Cd, X, s[11]); s[12] = fma(Cd, XX, s[12]);
    }

    // one shuffle fold (lane+32), then lanes 0..31 dump raw partials to LDS
#pragma unroll
    for (int i = 0; i < 13; i++) s[i] += __shfl_down(s[i], 32, 64);

    __syncthreads();                         // all I2S reads complete; alias as scratch
    double* scr = (double*)SMEM;             // 4 waves x 32 lanes x 13 f64 = 13312 B
    if (lane < 32) {
        double* o = scr + ((size_t)(wid * 32 + lane)) * 13;
#pragma unroll
        for (int i = 0; i < 13; i++) o[i] = s[i];
    }
    __syncthreads();

    if (tid < NACC) {
        // component -> (s index, Y power)
        const int comp[NACC] = {0,1,0, 2,3,2, 4,5,4, 6,5,4, 7,8,7, 9,8,7, 10,11,10, 12,11,10};
        const int ypw[NACC]  = {0,0,1, 0,0,1, 0,0,1, 0,1,2, 0,0,1, 0,1,2, 0,0,1,   0,1,2};
        const int cix = comp[tid], pw = ypw[tid];
        double acc = 0.0;
        for (int w = 0; w < 4; w++) {
            const double* basep = scr + ((size_t)(w * 32)) * 13 + cix;
            double part = 0.0;
            for (int l = 0; l < 32; l++) part += basep[(size_t)l * 13];
            const double Yw = (double)(y0 + w);
            const double f = (pw == 0) ? 1.0 : ((pw == 1) ? Yw : Yw * Yw);
            acc = fma(f, part, acc);
        }
        unsafeAtomicAdd(&S[b * NACC + tid], acc);
    }
}

extern "C" __global__ __launch_bounds__(256)
void k_solve(const double* __restrict__ S_it, const double* __restrict__ p_in,
             const int* __restrict__ done_in, double* __restrict__ p_out,
             int* __restrict__ done_out) {
    __shared__ double S[BB][NACC];
    const int tid = threadIdx.x;
    if (tid < BB * NACC) S[tid / NACC][tid % NACC] = S_it[tid];
    __syncthreads();
    if (tid >= BB) return;
    const int b = tid;
    if (done_in[b]) {
        done_out[b] = 1;
        for (int i = 0; i < NPAR; i++) p_out[b * NPAR + i] = p_in[b * NPAR + i];
        return;
    }
    const double* Sb = S[b];
    double bv[6] = {Sb[0], Sb[3], Sb[1], Sb[2], Sb[4], Sb[5]};
    double Hm[6][6];
    Hm[0][0] = Sb[6];  Hm[0][1] = Sb[12]; Hm[0][2] = Sb[7];  Hm[0][3] = Sb[8];  Hm[0][4] = Sb[13]; Hm[0][5] = Sb[14];
    Hm[1][1] = Sb[18]; Hm[1][2] = Sb[13]; Hm[1][3] = Sb[14]; Hm[1][4] = Sb[19]; Hm[1][5] = Sb[20];
    Hm[2][2] = Sb[9];  Hm[2][3] = Sb[10]; Hm[2][4] = Sb[15]; Hm[2][5] = Sb[16];
    Hm[3][3] = Sb[11]; Hm[3][4] = Sb[16]; Hm[3][5] = Sb[17];
    Hm[4][4] = Sb[21]; Hm[4][5] = Sb[22];
    Hm[5][5] = Sb[23];
    for (int i = 0; i < 6; i++)
        for (int jj = 0; jj < i; jj++) Hm[i][jj] = Hm[jj][i];
    for (int i = 0; i < 6; i++) Hm[i][i] += 1e-6;

    double Aa[6][7];
    for (int i = 0; i < 6; i++) {
        for (int jj = 0; jj < 6; jj++) Aa[i][jj] = Hm[i][jj];
        Aa[i][6] = bv[i];
    }
    for (int k = 0; k < 6; k++) {
        int piv = k;
        double mx = fabs(Aa[k][k]);
        for (int r = k + 1; r < 6; r++) {
            double v = fabs(Aa[r][k]);
            if (v > mx) { mx = v; piv = r; }
        }
        if (piv != k)
            for (int jj = k; jj < 7; jj++) { double t = Aa[k][jj]; Aa[k][jj] = Aa[piv][jj]; Aa[piv][jj] = t; }
        const double inv = 1.0 / Aa[k][k];
        for (int r = k + 1; r < 6; r++) {
            const double f = Aa[r][k] * inv;
            for (int jj = k; jj < 7; jj++) Aa[r][jj] -= f * Aa[k][jj];
        }
    }
    double dp[6];
    for (int i = 5; i >= 0; i--) {
        double sv = Aa[i][6];
        for (int jj = i + 1; jj < 6; jj++) sv -= Aa[i][jj] * dp[jj];
        dp[i] = sv / Aa[i][i];
    }
    const double nrm = sqrt(dp[0]*dp[0] + dp[1]*dp[1] + dp[2]*dp[2] + dp[3]*dp[3] + dp[4]*dp[4] + dp[5]*dp[5]);
    const int conv = (nrm < 1e-3) ? 1 : 0;

    const double* pc = p_in + b * NPAR;
    const double m00 = 1.0 + pc[2], m01 = pc[3], m02 = pc[0];
    const double m10 = pc[4], m11 = 1.0 + pc[5], m12 = pc[1];
    const double q00 = 1.0 + dp[2], q01 = dp[3], q02 = dp[0];
    const double q10 = dp[4], q11 = 1.0 + dp[5], q12 = dp[1];
    const double det = q00 * q11 - q01 * q10;
    const double i00 = q11 / det, i01 = -q01 / det;
    const double i10 = -q10 / det, i11 = q00 / det;
    const double it0 = -(i00 * q02 + i01 * q12);
    const double it1 = -(i10 * q02 + i11 * q12);
    const double n00 = m00 * i00 + m01 * i10;
    const double n01 = m00 * i01 + m01 * i11;
    const double n02 = m00 * it0 + m01 * it1 + m02;
    const double n10 = m10 * i00 + m11 * i10;
    const double n11 = m10 * i01 + m11 * i11;
    const double n12 = m10 * it0 + m11 * it1 + m12;
    p_out[b * NPAR + 0] = n02;
    p_out[b * NPAR + 1] = n12;
    p_out[b * NPAR + 2] = n00 - 1.0;
    p_out[b * NPAR + 3] = n01;
    p_out[b * NPAR + 4] = n10;
    p_out[b * NPAR + 5] = n11 - 1.0;
    done_out[b] = conv;
}

// 4-row x 128-col tiles over the FULL image (incl. borders). 2 px/thread.
extern "C" __global__ __launch_bounds__(256)
void k_final_map(const float* __restrict__ I1, const float* __restrict__ I2,
                 const double* __restrict__ p_fin, float* __restrict__ DI_out,
                 float* __restrict__ Iw_out, double* __restrict__ Sf) {
    __shared__ lf4 I2S[NR2 * PITCH2];
    __shared__ double wsum[4][2];
    const int tid = threadIdx.x;
    const int b = blockIdx.y;
    const int tix = blockIdx.x;                 // 0..287
    const int rt = tix / 3, win = tix - rt * 3;
    const int y0 = rt * 4;
    const int x0 = win * 128;
    const int WS2c = 140;
    const int sx0 = x0 - 6;

    const double* p = p_fin + b * NPAR;
    const double M00 = 1.0 + p[2], M01 = p[3], M02 = p[0];
    const double M10 = p[4], M11 = 1.0 + p[5], M12 = p[1];
    const float* I1b = I1 + (size_t)b * HWPIX * 3;
    const float* I2b = I2 + (size_t)b * HWPIX * 3;
    float* DIb = DI_out + (size_t)b * HWPIX * 3;
    float* Iwb = Iw_out + (size_t)b * HWPIX * 3;

    const double ygc = M10 * (double)(x0 + 64) + M11 * ((double)y0 + 1.5) + M12;
    const int r0 = (int)fmin(fmax(floor(ygc) - 3.0, -100000.0), 100000.0);

    for (int i = tid; i < NR2 * WS2c; i += 256) {
        const int r = i / WS2c, c = i - r * WS2c;
        const int gr = min(max(r0 + r, 0), HH - 1);    // clamped staging == clip-to-edge
        const int gc = min(max(sx0 + c, 0), WW - 1);
        const float* src = I2b + (gr * WW + gc) * 3;
        f2v ab = *(const f2v*)src;
        I2S[r * PITCH2 + c] = (lf4){ab.x, ab.y, src[2], 0.f};
    }
    __syncthreads();

    double rho_s = 0.0, cnt_s = 0.0;
#pragma unroll
    for (int step = 0; step < 2; step++) {
        const int idx = step * 256 + tid;        // 0..511
        const int row = idx >> 7, col = idx & 127;
        const int y = y0 + row, x = x0 + col;
        const int pix = y * WW + x;
        const double X = (double)x, Y = (double)y;
        const double xg = fma(M00, X, fma(M01, Y, M02));
        const double yg = fma(M10, X, fma(M11, Y, M12));
        const double fx = floor(xg), fy = floor(yg);
        const int xi = (int)fx, yi = (int)fy;
        const float tx = (float)(xg - fx), ty = (float)(yg - fy);
        const int sxi = xi - sx0, syi = yi - r0;
        const bool inwin = (sxi >= 1) && (sxi <= WS2c - 3) && (syi >= 1) && (syi <= NR2 - 3);

        float Iw[3];
        if (inwin) bicubic3_lds(I2S, sxi, syi, tx, ty, Iw);
        else       bicubic3_gen(I2b, xg, yg, Iw);

        Iwb[pix * 3 + 0] = Iw[0];
        Iwb[pix * 3 + 1] = Iw[1];
        Iwb[pix * 3 + 2] = Iw[2];

        const bool v1 = (x >= DEL) && (x < WW - DEL) && (y >= DEL) && (y < HH - DEL);
        const double gx = rint(xg), gy = rint(yg);
        const bool wm = (gx >= (double)DEL && gx <= (double)(WW - DEL) &&
                         gy >= (double)DEL && gy <= (double)(HH - DEL));
        const bool m = v1 && wm;
        const float* c = I1b + pix * 3;
        if (m) {
#pragma unroll
            for (int ch = 0; ch < 3; ch++) {
                const float d = Iw[ch] - c[ch];
                DIb[pix * 3 + ch] = d;
                const float u = d * 20.0f;
                const float rho = 0.005f * (sqrtf(fmaf(u, u, 1.0f)) - 1.0f);
                rho_s += (double)rho;
            }
            cnt_s += 3.0;
        } else {
            DIb[pix * 3 + 0] = 0.0f;
            DIb[pix * 3 + 1] = 0.0f;
            DIb[pix * 3 + 2] = 0.0f;
        }
    }
#pragma unroll
    for (int off = 32; off >= 1; off >>= 1) {
        rho_s += __shfl_down(rho_s, off, 64);
        cnt_s += __shfl_down(cnt_s, off, 64);
    }
    const int wid = tid >> 6, lane = tid & 63;
    if (lane == 0) { wsum[wid][0] = rho_s; wsum[wid][1] = cnt_s; }
    __syncthreads();
    if (tid < 2) {
        double sv = wsum[0][tid] + wsum[1][tid] + wsum[2][tid] + wsum[3][tid];
        unsafeAtomicAdd(&Sf[b * 2 + tid], sv);
    }
}

extern "C" __global__ void k_finish(const double* __restrict__ p_fin,
                                    const double* __restrict__ Sf,
                                    float* __restrict__ out) {
    const int tid = threadIdx.x;  // 64 threads
    if (tid < BB * NPAR) out[tid] = (float)p_fin[tid];           // pf
    if (tid >= 48 && tid < 48 + BB) {
        const int b = tid - 48;
        out[48 + b] = (float)(Sf[b * 2 + 0] / fmax(Sf[b * 2 + 1], 1.0));  // err
    }
}

extern "C" void kernel_launch(void* const* d_in, const int* in_sizes, int n_in,
                              void* d_out, int out_size, void* d_ws, size_t ws_size,
                              hipStream_t stream) {
    const float* I1 = (const float*)d_in[0];
    const float* I2 = (const float*)d_in[1];
    const float* p0 = (const float*)d_in[2];
    float* out = (float*)d_out;

    // ws layout (8B-aligned):
    // [0)      p_store (MAXIT+1)*48 doubles = 4992 B
    // [4992)   done    (MAXIT+1)*8 ints     = 416 B
    // [5408)   S_all   MAXIT*8*24 doubles   = 18432 B
    // [23840)  Sf      16 doubles           = 128 B
    double* p_store = (double*)d_ws;
    int* done_flags = (int*)((char*)d_ws + 4992);
    double* S_all = (double*)((char*)d_ws + 5408);
    double* Sf = (double*)((char*)d_ws + 23840);

    k_init<<<1, 256, 0, stream>>>(p0, p_store, done_flags, S_all, Sf);
    dim3 gridI(NRT4 * 3, BB), blkI(256);
    for (int it = 0; it < MAXIT; it++) {
        k_iter<<<gridI, blkI, 0, stream>>>(I1, I2,
                                           p_store + (size_t)it * BB * NPAR,
                                           done_flags + it * BB,
                                           S_all + (size_t)it * BB * NACC);
        k_solve<<<1, 256, 0, stream>>>(S_all + (size_t)it * BB * NACC,
                                       p_store + (size_t)it * BB * NPAR,
                                       done_flags + it * BB,
                                       p_store + (size_t)(it + 1) * BB * NPAR,
                                       done_flags + (it + 1) * BB);
    }
    float* DI_out = out + 56;
    float* Iw_out = out + 56 + (size_t)BB * HWPIX * 3;
    dim3 gridF(96 * 3, BB), blkF(256);
    k_final_map<<<gridF, blkF, 0, stream>>>(I1, I2, p_store + (size_t)MAXIT * BB * NPAR,
                                            DI_out, Iw_out, Sf);
    k_finish<<<1, 64, 0, stream>>>(p_store + (size_t)MAXIT * BB * NPAR, Sf, out);
}